// Round 15
// baseline (2307.825 us; speedup 1.0000x reference)
//
#include <hip/hip_runtime.h>
#include <hip/hip_bf16.h>

typedef __hip_bfloat16 bf16;
typedef unsigned char u8;
typedef unsigned long long u64;
typedef __attribute__((ext_vector_type(8))) short short8;
typedef __attribute__((ext_vector_type(8))) int i32x8;
typedef __attribute__((ext_vector_type(16))) float f32x16;
#define DI __device__ __forceinline__

union BF8 { int4 v; short8 s; bf16 h[8]; };
union BF4 { u64 u; bf16 h[4]; };
union U32B { int4 v[2]; i32x8 w; };

// ws layout (bytes):
// phase A: Xt @0 | projchunk @67,108,864 | cA @117,440,512 | cB @184,549,376
//          wproj @218,103,808
// phase B: transpose -> cAT @0, cBT @67,108,864 (over dead Xt/projchunk)
//          to_fp8 (SEPARATE kernel; fusing it into transpose races with the
//          cA read -- R14 NaN) -> cAT8 @117,440,512 (over dead cA)
// phase C: conv1 -> x1 @184,549,376; conv3/5/7 (MX fp8) -> x3 @0,
//          x5 @33,554,432, x7 @67,108,864
// parts @234,881,024 (32 KB): conv3 @0, conv5 @+2048, conv7 @+4096, conv1 @+6144
// wf3 @234,913,792 | wf5 @236,093,440 | wf7 @239,370,240 | wb1 @245,792,768

DI u8 f32_fp8(float v) {
  return (u8)(__builtin_amdgcn_cvt_pk_fp8_f32(v, 0.f, 0, false) & 0xff);
}

// ---------------------------------------------------------------- weight prep
// MX layout for wf3/5/7 (x256): addr = (((tap*8+cc2)*2+g)*128+oc)*32 + o,
//   ic = (cc2*2+g)*32 + ((o>>3)&1)*16 + ((o>>4)&1)*8 + (o&7)   [matches cAT8]
__global__ __launch_bounds__(256) void prep_w_kernel(
    const float* __restrict__ w3, const float* __restrict__ w5,
    const float* __restrict__ w7, const float* __restrict__ w1,
    const float* __restrict__ wq_st, const float* __restrict__ wk_st,
    const float* __restrict__ wv_st, const float* __restrict__ wq_phy,
    const float* __restrict__ wk_phy, const float* __restrict__ wv_phy,
    u8* __restrict__ wf3, u8* __restrict__ wf5,
    u8* __restrict__ wf7, bf16* __restrict__ wb1, bf16* __restrict__ wp)
{
  const int N3 = 9 * 65536, N5 = 25 * 65536, N7 = 49 * 65536, N1 = 65536;
  const int NP = 6 * 16384;
  const int total = N3 + N5 + N7 + N1 + NP;
  for (int i = blockIdx.x * 256 + threadIdx.x; i < total; i += gridDim.x * 256) {
    if (i < N3 + N5 + N7) {
      const float* w; int k; int taps;
      u8* dst;
      if (i < N3)           { w = w3; k = i;            taps = 9;  dst = wf3; }
      else if (i < N3 + N5) { w = w5; k = i - N3;       taps = 25; dst = wf5; }
      else                  { w = w7; k = i - N3 - N5;  taps = 49; dst = wf7; }
      int tap = k >> 16, rem = k & 65535;
      int cc2 = rem >> 13, r2 = rem & 8191;
      int g = r2 >> 12, r3 = r2 & 4095;
      int oc = r3 >> 5, o = r3 & 31;
      int ic = (cc2 * 2 + g) * 32 + ((o >> 3) & 1) * 16 + ((o >> 4) & 1) * 8 + (o & 7);
      dst[k] = f32_fp8(w[(size_t)(oc * 512 + ic) * taps + tap] * 256.0f);
    } else if (i < N3 + N5 + N7 + N1) {
      int k = i - N3 - N5 - N7;
      int icg = k >> 10, oc = (k >> 3) & 127, j = k & 7;
      wb1[k] = __float2bfloat16(w1[(size_t)oc * 512 + icg * 8 + j]);
    } else {
      int k = i - N3 - N5 - N7 - N1;
      int m = k >> 14, r = k & 16383;
      float v;
      switch (m) {
        case 0: v = wq_st[r]; break;
        case 1: v = wk_st[r]; break;
        case 2: v = wv_st[r]; break;
        case 3: v = wq_phy[r]; break;
        case 4: v = wk_phy[r]; break;
        default: v = wv_phy[r]; break;
      }
      wp[k] = __float2bfloat16(v);
    }
  }
}

// ---------------------------------------------------------------- input transpose
__global__ __launch_bounds__(256) void xpose_in_kernel(
    const float* __restrict__ st, const float* __restrict__ phy,
    bf16* __restrict__ Xt)
{
  __shared__ __align__(16) short Tb[64 * 72];
  const int x = blockIdx.x, b = blockIdx.y;
  const int t = x >> 5, rem = x & 31;
  const int ict = rem >> 4, post = rem & 15;
  const int ic0 = ict * 64, pos0 = post * 64;
  const int tid = threadIdx.x;
  const int rowi = tid >> 2, sub = tid & 3;
  const float* X = t ? phy : st;

  const float* src = X + ((size_t)b * 128 + ic0 + rowi) * 1024 + pos0 + sub * 16;
  #pragma unroll
  for (int q = 0; q < 4; ++q) {
    float4 v = *(const float4*)(src + q * 4);
    BF4 pk;
    pk.h[0] = __float2bfloat16(v.x); pk.h[1] = __float2bfloat16(v.y);
    pk.h[2] = __float2bfloat16(v.z); pk.h[3] = __float2bfloat16(v.w);
    *(u64*)&Tb[rowi * 72 + sub * 16 + q * 4] = pk.u;
  }
  __syncthreads();
  short tmp[16];
  #pragma unroll
  for (int j = 0; j < 16; ++j) tmp[j] = Tb[(sub * 16 + j) * 72 + rowi];
  bf16* dst = Xt + (((size_t)t * 128 + b) * 1024 + pos0 + rowi) * 128 + ic0 + sub * 16;
  *(int4*)dst       = ((int4*)tmp)[0];
  *(int4*)(dst + 8) = ((int4*)tmp)[1];
}

// ---------------------------------------------------------------- MFMA projections
__global__ __launch_bounds__(256) void proj_mfma(
    const bf16* __restrict__ Xt, const bf16* __restrict__ wproj,
    const float* __restrict__ b0, const float* __restrict__ b1,
    const float* __restrict__ b2, const float* __restrict__ b3,
    const float* __restrict__ b4, const float* __restrict__ b5,
    bf16* __restrict__ pc, int cb)
{
  const int pt = blockIdx.x, b = blockIdx.y;
  const int tid = threadIdx.x, wave = tid >> 6, lane = tid & 63;
  const int col = lane & 31, kg = lane >> 5;
  const int pos = pt * 128 + wave * 32 + col;

  f32x16 acc[6];
  #pragma unroll
  for (int m = 0; m < 6; ++m)
    #pragma unroll
    for (int e = 0; e < 16; ++e) acc[m][e] = 0.f;

  const bf16* xst = Xt + ((size_t)b * 1024 + pos) * 128 + kg * 8;
  const bf16* xph = xst + (size_t)128 * 1024 * 128;
  const bf16* wl = wproj + (size_t)(cb + col) * 128 + kg * 8;

  #pragma unroll
  for (int kst = 0; kst < 8; ++kst) {
    short8 bst = *(const short8*)&xst[kst * 16];
    short8 bph = *(const short8*)&xph[kst * 16];
    #pragma unroll
    for (int m = 0; m < 6; ++m) {
      BF8 a; a.v = *(const int4*)&wl[(size_t)m * 16384 + kst * 16];
      acc[m] = __builtin_amdgcn_mfma_f32_32x32x16_bf16(a.s, m < 3 ? bst : bph, acc[m], 0, 0, 0);
    }
  }
  const float* biases[6] = { b0, b1, b2, b3, b4, b5 };
  #pragma unroll
  for (int m = 0; m < 6; ++m) {
    #pragma unroll
    for (int r = 0; r < 16; ++r) {
      const int ocl = (r & 3) + 8 * (r >> 2) + 4 * kg;
      float v = acc[m][r] + biases[m][cb + ocl];
      pc[(((size_t)m * 128 + b) * 32 + ocl) * 1024 + pos] = __float2bfloat16(v);
    }
  }
}

// ---------------------------------------------------------------- MFMA attention
DI void softmax_rows(float p[16])
{
  #pragma unroll
  for (int r = 0; r < 16; ++r) {
    float m = p[r];
    m = fmaxf(m, __shfl_xor(m, 1));
    m = fmaxf(m, __shfl_xor(m, 2));
    m = fmaxf(m, __shfl_xor(m, 4));
    m = fmaxf(m, __shfl_xor(m, 8));
    m = fmaxf(m, __shfl_xor(m, 16));
    float e = __expf(p[r] - m);
    float s = e;
    s += __shfl_xor(s, 1); s += __shfl_xor(s, 2); s += __shfl_xor(s, 4);
    s += __shfl_xor(s, 8); s += __shfl_xor(s, 16);
    p[r] = __fdividef(e, s);
  }
}

template<bool U8OUT>
DI void attn_one_mfma(const BF8& qa0, const BF8& qa1,
                      const bf16* __restrict__ KT, const bf16* __restrict__ VT,
                      bf16* __restrict__ P,
                      const float* __restrict__ resid, void* outp, int lane)
{
  const int col = lane & 31, kg = lane >> 5;
  f32x16 acc;
  #pragma unroll
  for (int e = 0; e < 16; ++e) acc[e] = 0.f;
  BF8 kb0, kb1;
  kb0.v = *(const int4*)&KT[col * 40 + kg * 8];
  kb1.v = *(const int4*)&KT[col * 40 + 16 + kg * 8];
  acc = __builtin_amdgcn_mfma_f32_32x32x16_bf16(qa0.s, kb0.s, acc, 0, 0, 0);
  acc = __builtin_amdgcn_mfma_f32_32x32x16_bf16(qa1.s, kb1.s, acc, 0, 0, 0);
  float p[16];
  #pragma unroll
  for (int r = 0; r < 16; ++r) p[r] = acc[r];
  softmax_rows(p);
  __syncthreads();
  #pragma unroll
  for (int r = 0; r < 16; ++r) {
    int row = (r & 3) + 8 * (r >> 2) + 4 * kg;
    P[row * 40 + col] = __float2bfloat16(p[r]);
  }
  __syncthreads();
  BF8 pa0, pa1, vb0, vb1;
  pa0.v = *(const int4*)&P[col * 40 + kg * 8];
  pa1.v = *(const int4*)&P[col * 40 + 16 + kg * 8];
  vb0.v = *(const int4*)&VT[col * 40 + kg * 8];
  vb1.v = *(const int4*)&VT[col * 40 + 16 + kg * 8];
  #pragma unroll
  for (int e = 0; e < 16; ++e) acc[e] = 0.f;
  acc = __builtin_amdgcn_mfma_f32_32x32x16_bf16(pa0.s, vb0.s, acc, 0, 0, 0);
  acc = __builtin_amdgcn_mfma_f32_32x32x16_bf16(pa1.s, vb1.s, acc, 0, 0, 0);
  #pragma unroll
  for (int r = 0; r < 16; ++r) p[r] = acc[r];
  softmax_rows(p);
  if constexpr (!U8OUT) {
    bf16* op = (bf16*)outp;
    #pragma unroll
    for (int r = 0; r < 16; ++r) {
      int row = (r & 3) + 8 * (r >> 2) + 4 * kg;
      int off = row * 32 + col;
      op[off] = __float2bfloat16(p[r] + resid[off]);
    }
  } else {
    u8* op = (u8*)outp;
    #pragma unroll
    for (int r = 0; r < 16; ++r) {
      int row = (r & 3) + 8 * (r >> 2) + 4 * kg;
      op[row * 32 + col] = (u8)fminf(p[r] * 256.f + 0.5f, 255.f);
    }
  }
}

__global__ __launch_bounds__(64) void attn_mfma_kernel(
    const bf16* __restrict__ pc,
    const float* __restrict__ st, const float* __restrict__ phy,
    bf16* __restrict__ cA, u8* __restrict__ cB, int cb)
{
  __shared__ __align__(16) bf16 KTst[32 * 40], VTst[32 * 40];
  __shared__ __align__(16) bf16 KTph[32 * 40], VTph[32 * 40];
  __shared__ __align__(16) bf16 P[32 * 40];
  const int cl = blockIdx.x, b = blockIdx.y;
  const int c = cb + cl;
  const int lane = threadIdx.x;
  const size_t mstride = (size_t)128 * 32 * 1024;
  const bf16* p0 = pc + ((size_t)b * 32 + cl) * 1024;
  const size_t bc = ((size_t)b * 128 + c) * 1024;

  {
    const int w = lane >> 1, k0 = (lane & 1) * 16;
    const int off = w * 32 + k0;
    bf16* dsts[4] = { KTst, VTst, KTph, VTph };
    const int ms[4] = { 1, 2, 4, 5 };
    #pragma unroll
    for (int t = 0; t < 4; ++t) {
      BF8 r0, r1;
      r0.v = *(const int4*)&p0[(size_t)ms[t] * mstride + off];
      r1.v = *(const int4*)&p0[(size_t)ms[t] * mstride + off + 8];
      #pragma unroll
      for (int j = 0; j < 8; ++j) {
        dsts[t][(k0 + j) * 40 + w]     = r0.h[j];
        dsts[t][(k0 + 8 + j) * 40 + w] = r1.h[j];
      }
    }
  }
  const int col = lane & 31, kg = lane >> 5;
  BF8 qst0, qst1, qph0, qph1;
  qst0.v = *(const int4*)&p0[col * 32 + kg * 8];
  qst1.v = *(const int4*)&p0[col * 32 + 16 + kg * 8];
  qph0.v = *(const int4*)&p0[3 * mstride + col * 32 + kg * 8];
  qph1.v = *(const int4*)&p0[3 * mstride + col * 32 + 16 + kg * 8];
  __syncthreads();

  bf16* aA = cA + (size_t)b * 256 * 1024 + (size_t)c * 1024;
  u8*   aB = cB + (size_t)b * 256 * 1024 + (size_t)c * 1024;
  attn_one_mfma<false>(qst0, qst1, KTst, VTst, P, st + bc,  aA,          lane);
  attn_one_mfma<false>(qph0, qph1, KTph, VTph, P, phy + bc, aA + 131072, lane);
  attn_one_mfma<true >(qph0, qph1, KTst, VTst, P, nullptr,  aB,          lane);
  attn_one_mfma<true >(qst0, qst1, KTph, VTph, P, nullptr,  aB + 131072, lane);
}

// ---------------------------------------------------------------- concat transpose
__global__ __launch_bounds__(256) void transpose_kernel(
    const bf16* __restrict__ cA, const u8* __restrict__ cB,
    bf16* __restrict__ cAT, u8* __restrict__ cBT)
{
  __shared__ __align__(16) short Tb[64 * 72];
  __shared__ __align__(16) u8 T8[64 * 80];
  const int x = blockIdx.x, b = blockIdx.y;
  const int cht = x >> 4, post = x & 15;
  const int pos0 = post * 64;
  const int tid = threadIdx.x;
  const int rowi = tid >> 2, sub = tid & 3;

  if (cht < 4) {
    const int ch0 = cht * 64;
    const bf16* src = cA + ((size_t)b * 256 + ch0 + rowi) * 1024 + pos0 + sub * 16;
    *(int4*)&Tb[rowi * 72 + sub * 16]     = *(const int4*)src;
    *(int4*)&Tb[rowi * 72 + sub * 16 + 8] = *(const int4*)(src + 8);
    __syncthreads();
    short tmp[16];
    #pragma unroll
    for (int j = 0; j < 16; ++j) tmp[j] = Tb[(sub * 16 + j) * 72 + rowi];
    bf16* dst = cAT + ((size_t)b * 1024 + pos0 + rowi) * 256 + ch0 + sub * 16;
    *(int4*)dst       = ((int4*)tmp)[0];
    *(int4*)(dst + 8) = ((int4*)tmp)[1];
  } else {
    const int ch0 = (cht - 4) * 64;
    const u8* src = cB + ((size_t)b * 256 + ch0 + rowi) * 1024 + pos0 + sub * 16;
    *(int4*)&T8[rowi * 80 + sub * 16] = *(const int4*)src;
    __syncthreads();
    u8 tmp[16];
    #pragma unroll
    for (int j = 0; j < 16; ++j) tmp[j] = T8[(sub * 16 + j) * 80 + rowi];
    u8* dst = cBT + ((size_t)b * 1024 + pos0 + rowi) * 256 + ch0 + sub * 16;
    *(int4*)dst = *(int4*)tmp;
  }
}

// ---------------------------------------------------------------- fp8 conversion pass
__global__ __launch_bounds__(256) void to_fp8_kernel(
    const bf16* __restrict__ cAT, const u8* __restrict__ cBT,
    u8* __restrict__ cAT8)
{
  const int idx = blockIdx.x * 256 + threadIdx.x;
  const int g = idx & 31;
  const size_t bp = (size_t)(idx >> 5);
  const int c0 = g * 16;
  float v[16];
  if (c0 < 256) {
    BF8 lo, hi;
    lo.v = *(const int4*)&cAT[bp * 256 + c0];
    hi.v = *(const int4*)&cAT[bp * 256 + c0 + 8];
    #pragma unroll
    for (int j = 0; j < 8; ++j) {
      v[j]     = __bfloat162float(lo.h[j]) * 16.0f;
      v[8 + j] = __bfloat162float(hi.h[j]) * 16.0f;
    }
  } else {
    u64 raw0 = *(const u64*)&cBT[bp * 256 + (c0 - 256)];
    u64 raw1 = *(const u64*)&cBT[bp * 256 + (c0 - 256) + 8];
    #pragma unroll
    for (int j = 0; j < 8; ++j) {
      v[j]     = (float)((raw0 >> (8 * j)) & 255u) * 0.0625f;
      v[8 + j] = (float)((raw1 >> (8 * j)) & 255u) * 0.0625f;
    }
  }
  unsigned lo0 = (__builtin_amdgcn_cvt_pk_fp8_f32(v[0], v[1], 0, false) & 0xffff)
               | ((__builtin_amdgcn_cvt_pk_fp8_f32(v[2], v[3], 0, false) & 0xffff) << 16);
  unsigned hi0 = (__builtin_amdgcn_cvt_pk_fp8_f32(v[4], v[5], 0, false) & 0xffff)
               | ((__builtin_amdgcn_cvt_pk_fp8_f32(v[6], v[7], 0, false) & 0xffff) << 16);
  unsigned lo1 = (__builtin_amdgcn_cvt_pk_fp8_f32(v[8], v[9], 0, false) & 0xffff)
               | ((__builtin_amdgcn_cvt_pk_fp8_f32(v[10], v[11], 0, false) & 0xffff) << 16);
  unsigned hi1 = (__builtin_amdgcn_cvt_pk_fp8_f32(v[12], v[13], 0, false) & 0xffff)
               | ((__builtin_amdgcn_cvt_pk_fp8_f32(v[14], v[15], 0, false) & 0xffff) << 16);
  u64 run0 = (u64)lo0 | ((u64)hi0 << 32);
  u64 run1 = (u64)lo1 | ((u64)hi1 << 32);
  const int sp = (c0 >> 4) & 1;
  u8* d = cAT8 + bp * 512 + (c0 & ~31);
  *(u64*)(d + 8 * sp)      = run0;
  *(u64*)(d + 16 + 8 * sp) = run1;
}

// ---------------------------------------------------------------- staging (bf16)
template<int PCX, int NIT, int H0>
DI void stage_tile(const bf16* cAT, const u8* cBT, short* Xs,
                   int b, int r0, int ic0, int tid)
{
  for (int e = tid; e < NIT; e += 256) {
    int i = e / (PCX * 4);
    int rem = e - i * (PCX * 4);
    int cx = rem >> 2, part = rem & 3;
    int ir = r0 - H0 + i, c = cx - H0;
    int4 val = make_int4(0, 0, 0, 0);
    if ((unsigned)ir < 32u && (unsigned)c < 32u) {
      size_t pbase = ((size_t)b * 1024 + ir * 32 + c) * 256;
      if (ic0 < 256) {
        val = *(const int4*)&cAT[pbase + ic0 + part * 8];
      } else {
        u64 u = *(const u64*)&cBT[pbase + (ic0 - 256) + part * 8];
        BF8 t;
        #pragma unroll
        for (int j = 0; j < 8; ++j)
          t.h[j] = __float2bfloat16((float)((u >> (8 * j)) & 255u) * 0.00390625f);
        val = t.v;
      }
    }
    *(int4*)&Xs[(i * PCX + cx) * 40 + part * 8] = val;
  }
}

// ---------------------------------------------------------------- bf16 MFMA conv (conv1)
template<int KS>
__global__ __launch_bounds__(256, 2) void conv_mfma(
    const bf16* __restrict__ cAT, const u8* __restrict__ cBT,
    const bf16* __restrict__ wt, const float* __restrict__ bias,
    bf16* __restrict__ xout, float* __restrict__ partials)
{
  constexpr int H0 = KS / 2;
  constexpr int PCX = 32 + 2 * H0;
  constexpr int ROWS = 16 + 2 * H0;
  constexpr int NIT = ROWS * PCX * 4;
  __shared__ __align__(16) short Xs[ROWS * PCX * 40];
  __shared__ float rs[256], rq[256];
  const int h = blockIdx.x;
  const int logical = (h & 7) * 64 + (h >> 3);
  const int b = logical >> 2, tix = logical & 3;
  const int ot = tix >> 1, rt = tix & 1;
  const int oc0 = ot * 64, r0 = rt * 16;
  const int tid = threadIdx.x;
  const int wv = tid >> 6, lane = tid & 63;
  const int col = lane & 31, kg = lane >> 5;

  f32x16 acc[2][4];
  #pragma unroll
  for (int i = 0; i < 2; ++i)
    #pragma unroll
    for (int j = 0; j < 4; ++j)
      #pragma unroll
      for (int e = 0; e < 16; ++e) acc[i][j][e] = 0.f;

  for (int cc = 0; cc < 16; ++cc) {
    const int ic0 = cc * 32;
    stage_tile<PCX, NIT, H0>(cAT, cBT, Xs, b, r0, ic0, tid);
    __syncthreads();

    #pragma unroll 1
    for (int ky = 0; ky < KS; ++ky) {
      #pragma unroll
      for (int kx = 0; kx < KS; ++kx) {
        const int tap = ky * KS + kx;
        BF8 a[2][2];
        #pragma unroll
        for (int ob = 0; ob < 2; ++ob)
          #pragma unroll
          for (int kt = 0; kt < 2; ++kt) {
            int icg = cc * 4 + kt * 2 + kg;
            a[ob][kt].v = *(const int4*)&wt[(((size_t)tap * 64 + icg) * 128 + oc0 + ob * 32 + col) * 8];
          }
        #pragma unroll
        for (int rr = 0; rr < 4; ++rr) {
          int entry = ((wv * 4 + rr + ky) * PCX + col + kx) * 40;
          #pragma unroll
          for (int kt = 0; kt < 2; ++kt) {
            short8 bf = *(const short8*)&Xs[entry + (kt * 2 + kg) * 8];
            acc[0][rr] = __builtin_amdgcn_mfma_f32_32x32x16_bf16(a[0][kt].s, bf, acc[0][rr], 0, 0, 0);
            acc[1][rr] = __builtin_amdgcn_mfma_f32_32x32x16_bf16(a[1][kt].s, bf, acc[1][rr], 0, 0, 0);
          }
        }
      }
    }
    __syncthreads();
  }

  float lsum = 0.f, lsq = 0.f;
  #pragma unroll
  for (int ob = 0; ob < 2; ++ob)
    #pragma unroll
    for (int rr = 0; rr < 4; ++rr) {
      const int row = r0 + wv * 4 + rr;
      #pragma unroll
      for (int r = 0; r < 16; ++r) {
        const int oc = oc0 + ob * 32 + (r & 3) + 8 * (r >> 2) + 4 * kg;
        float v = acc[ob][rr][r];
        if (bias) v += bias[oc];
        xout[((size_t)b * 128 + oc) * 1024 + row * 32 + col] = __float2bfloat16(v);
        lsum += v; lsq += v * v;
      }
    }
  rs[tid] = lsum; rq[tid] = lsq;
  __syncthreads();
  for (int s = 128; s > 0; s >>= 1) {
    if (tid < s) { rs[tid] += rs[tid + s]; rq[tid] += rq[tid + s]; }
    __syncthreads();
  }
  if (tid == 0) {
    partials[((size_t)b * 4 + tix) * 2]     = rs[0];
    partials[((size_t)b * 4 + tix) * 2 + 1] = rq[0];
  }
}

// ---------------------------------------------------------------- MX fp8 conv (KS=3,5,7)
// ob=4 x rr=2, 8-row tiles: halves LDS-read traffic per MFMA vs the R13
// ob=2 x rr=4 shape (A-loads double but are wave-shared L1 broadcasts on the
// TA pipe, parallel to LDS). 3 blocks/CU (LDS 42.6 KB @ KS=7). Grid 512,
// XCD-swizzled. Partials: 4/batch (rt in [0,4)).
template<int KS>
__global__ __launch_bounds__(256, 3) void conv_mx(
    const u8* __restrict__ cAT8, const u8* __restrict__ wf,
    bf16* __restrict__ xout, float* __restrict__ partials)
{
  constexpr int H0 = KS / 2;
  constexpr int PCX = 32 + 2 * H0;
  constexpr int ROWS = 8 + 2 * H0;
  constexpr int NIT = ROWS * PCX * 4;              // 16-B units
  __shared__ __align__(16) u8 Xs[ROWS * PCX * 80];
  __shared__ float rs[256], rq[256];
  const int h = blockIdx.x;
  const int logical = (h & 7) * 64 + (h >> 3);
  const int b = logical >> 2, rt = logical & 3;
  const int r0 = rt * 8;
  const int tid = threadIdx.x;
  const int wv = tid >> 6, lane = tid & 63;
  const int col = lane & 31, g = lane >> 5;

  f32x16 acc[4][2];
  #pragma unroll
  for (int i = 0; i < 4; ++i)
    #pragma unroll
    for (int j = 0; j < 2; ++j)
      #pragma unroll
      for (int e = 0; e < 16; ++e) acc[i][j][e] = 0.f;

  for (int cc2 = 0; cc2 < 8; ++cc2) {
    for (int e = tid; e < NIT; e += 256) {
      int entry = e >> 2, hf = e & 3;
      int i = entry / PCX, cx = entry - i * PCX;
      int ir = r0 - H0 + i, c = cx - H0;
      int4 val = make_int4(0, 0, 0, 0);
      if ((unsigned)ir < 32u && (unsigned)c < 32u)
        val = *(const int4*)&cAT8[((size_t)b * 1024 + ir * 32 + c) * 512 + cc2 * 64 + hf * 16];
      *(int4*)&Xs[entry * 80 + hf * 16] = val;
    }
    __syncthreads();

    #pragma unroll 1
    for (int ky = 0; ky < KS; ++ky) {
      #pragma unroll
      for (int kx = 0; kx < KS; ++kx) {
        const int tap = ky * KS + kx;
        const size_t wbase = (((size_t)tap * 8 + cc2) * 2 + g) * 128;
        U32B bf0, bf1;
        {
          const int e0 = ((wv * 2 + 0 + ky) * PCX + col + kx) * 80 + g * 32;
          const int e1 = ((wv * 2 + 1 + ky) * PCX + col + kx) * 80 + g * 32;
          bf0.v[0] = *(const int4*)&Xs[e0];
          bf0.v[1] = *(const int4*)&Xs[e0 + 16];
          bf1.v[0] = *(const int4*)&Xs[e1];
          bf1.v[1] = *(const int4*)&Xs[e1 + 16];
        }
        #pragma unroll
        for (int ob = 0; ob < 4; ++ob) {
          U32B a;
          a.v[0] = *(const int4*)&wf[(wbase + ob * 32 + col) * 32];
          a.v[1] = *(const int4*)&wf[(wbase + ob * 32 + col) * 32 + 16];
          acc[ob][0] = __builtin_amdgcn_mfma_scale_f32_32x32x64_f8f6f4(
              a.w, bf0.w, acc[ob][0], 0, 0, 0, 0x7f7f7f7f, 0, 0x7f7f7f7f);
          acc[ob][1] = __builtin_amdgcn_mfma_scale_f32_32x32x64_f8f6f4(
              a.w, bf1.w, acc[ob][1], 0, 0, 0, 0x7f7f7f7f, 0, 0x7f7f7f7f);
        }
      }
    }
    __syncthreads();
  }

  float lsum = 0.f, lsq = 0.f;
  #pragma unroll
  for (int ob = 0; ob < 4; ++ob)
    #pragma unroll
    for (int rr = 0; rr < 2; ++rr) {
      const int row = r0 + wv * 2 + rr;
      #pragma unroll
      for (int r = 0; r < 16; ++r) {
        const int oc = ob * 32 + (r & 3) + 8 * (r >> 2) + 4 * g;
        float v = acc[ob][rr][r] * (1.0f / 4096.0f);
        xout[((size_t)b * 128 + oc) * 1024 + row * 32 + col] = __float2bfloat16(v);
        lsum += v; lsq += v * v;
      }
    }
  rs[tid] = lsum; rq[tid] = lsq;
  __syncthreads();
  for (int s = 128; s > 0; s >>= 1) {
    if (tid < s) { rs[tid] += rs[tid + s]; rq[tid] += rq[tid + s]; }
    __syncthreads();
  }
  if (tid == 0) {
    partials[((size_t)b * 4 + rt) * 2]     = rs[0];
    partials[((size_t)b * 4 + rt) * 2 + 1] = rq[0];
  }
}

// ---------------------------------------------------------------- LN + combine (4 partials each)
__global__ __launch_bounds__(256) void final_kernel(
    const bf16* __restrict__ x3, const bf16* __restrict__ x5,
    const bf16* __restrict__ x7, const bf16* __restrict__ x1c,
    const float* __restrict__ p3, const float* __restrict__ p5,
    const float* __restrict__ p7, const float* __restrict__ p1,
    const float* __restrict__ g3, const float* __restrict__ be3,
    const float* __restrict__ g5, const float* __restrict__ be5,
    const float* __restrict__ g7, const float* __restrict__ be7,
    const float* __restrict__ g1, const float* __restrict__ be1,
    float* __restrict__ out)
{
  const int blk = blockIdx.x, b = blockIdx.y, tid = threadIdx.x;
  float s3 = 0, q3 = 0, s5 = 0, q5 = 0, s7 = 0, q7 = 0, s1 = 0, q1 = 0;
  #pragma unroll
  for (int i = 0; i < 4; ++i) {
    int o = (b * 4 + i) * 2;
    s3 += p3[o]; q3 += p3[o + 1];
    s5 += p5[o]; q5 += p5[o + 1];
    s7 += p7[o]; q7 += p7[o + 1];
    s1 += p1[o]; q1 += p1[o + 1];
  }
  const float inv = 1.0f / 131072.0f;
  float mu3 = s3 * inv, r3 = rsqrtf(fmaxf(q3 * inv - mu3 * mu3, 0.f) + 1e-5f);
  float mu5 = s5 * inv, r5 = rsqrtf(fmaxf(q5 * inv - mu5 * mu5, 0.f) + 1e-5f);
  float mu7 = s7 * inv, r7 = rsqrtf(fmaxf(q7 * inv - mu7 * mu7, 0.f) + 1e-5f);
  float mu1 = s1 * inv, r1 = rsqrtf(fmaxf(q1 * inv - mu1 * mu1, 0.f) + 1e-5f);
  const size_t bb = (size_t)b * 131072;
  for (int it = 0; it < 8; ++it) {
    int e0 = (it * 2048 + blk * 256 + tid) * 8;
    BF8 a3, a5, a7, a1;
    a3.v = *(const int4*)&x3[bb + e0];
    a5.v = *(const int4*)&x5[bb + e0];
    a7.v = *(const int4*)&x7[bb + e0];
    a1.v = *(const int4*)&x1c[bb + e0];
    float G3[8], B3[8], G5[8], B5[8], G7[8], B7[8], G1[8], B1[8];
    *(float4*)&G3[0] = *(const float4*)&g3[e0];  *(float4*)&G3[4] = *(const float4*)&g3[e0 + 4];
    *(float4*)&B3[0] = *(const float4*)&be3[e0]; *(float4*)&B3[4] = *(const float4*)&be3[e0 + 4];
    *(float4*)&G5[0] = *(const float4*)&g5[e0];  *(float4*)&G5[4] = *(const float4*)&g5[e0 + 4];
    *(float4*)&B5[0] = *(const float4*)&be5[e0]; *(float4*)&B5[4] = *(const float4*)&be5[e0 + 4];
    *(float4*)&G7[0] = *(const float4*)&g7[e0];  *(float4*)&G7[4] = *(const float4*)&g7[e0 + 4];
    *(float4*)&B7[0] = *(const float4*)&be7[e0]; *(float4*)&B7[4] = *(const float4*)&be7[e0 + 4];
    *(float4*)&G1[0] = *(const float4*)&g1[e0];  *(float4*)&G1[4] = *(const float4*)&g1[e0 + 4];
    *(float4*)&B1[0] = *(const float4*)&be1[e0]; *(float4*)&B1[4] = *(const float4*)&be1[e0 + 4];
    float res[8];
    #pragma unroll
    for (int j = 0; j < 8; ++j) {
      float v3 = (__bfloat162float(a3.h[j]) - mu3) * r3 * G3[j] + B3[j];
      float v5 = (__bfloat162float(a5.h[j]) - mu5) * r5 * G5[j] + B5[j];
      float v7 = (__bfloat162float(a7.h[j]) - mu7) * r7 * G7[j] + B7[j];
      float m = (v3 + v5 + v7) * (1.0f / 3.0f);
      float sg = 1.0f / (1.0f + __expf(-m));
      float v1 = (__bfloat162float(a1.h[j]) - mu1) * r1 * G1[j] + B1[j];
      res[j] = sg + v1;
    }
    *(float4*)&out[bb + e0]     = make_float4(res[0], res[1], res[2], res[3]);
    *(float4*)&out[bb + e0 + 4] = make_float4(res[4], res[5], res[6], res[7]);
  }
}

// ---------------------------------------------------------------- launch
extern "C" void kernel_launch(void* const* d_in, const int* in_sizes, int n_in,
                              void* d_out, int out_size, void* d_ws, size_t ws_size,
                              hipStream_t stream)
{
  (void)in_sizes; (void)n_in; (void)out_size; (void)ws_size;
  const float* st     = (const float*)d_in[0];
  const float* phy    = (const float*)d_in[1];
  const float* wq_st  = (const float*)d_in[2];
  const float* bq_st  = (const float*)d_in[3];
  const float* wk_st  = (const float*)d_in[4];
  const float* bk_st  = (const float*)d_in[5];
  const float* wv_st  = (const float*)d_in[6];
  const float* bv_st  = (const float*)d_in[7];
  const float* wq_phy = (const float*)d_in[8];
  const float* bq_phy = (const float*)d_in[9];
  const float* wk_phy = (const float*)d_in[10];
  const float* bk_phy = (const float*)d_in[11];
  const float* wv_phy = (const float*)d_in[12];
  const float* bv_phy = (const float*)d_in[13];
  const float* w3  = (const float*)d_in[14];
  const float* g3  = (const float*)d_in[15];
  const float* be3 = (const float*)d_in[16];
  const float* w5  = (const float*)d_in[17];
  const float* g5  = (const float*)d_in[18];
  const float* be5 = (const float*)d_in[19];
  const float* w7  = (const float*)d_in[20];
  const float* g7  = (const float*)d_in[21];
  const float* be7 = (const float*)d_in[22];
  const float* w1  = (const float*)d_in[23];
  const float* g1  = (const float*)d_in[24];
  const float* be1 = (const float*)d_in[25];
  const float* b1  = (const float*)d_in[26];

  char* ws = (char*)d_ws;
  // phase A
  bf16* Xt        = (bf16*)ws;
  bf16* projchunk = (bf16*)(ws + 67108864ULL);
  bf16* cA        = (bf16*)(ws + 117440512ULL);
  u8*   cB        = (u8*)(ws + 184549376ULL);
  bf16* wproj     = (bf16*)(ws + 218103808ULL);
  // phase B/C
  bf16* cAT       = (bf16*)ws;
  u8*   cBT       = (u8*)(ws + 67108864ULL);
  u8*   cAT8      = (u8*)(ws + 117440512ULL);
  bf16* x1b       = (bf16*)(ws + 184549376ULL);
  bf16* x3b       = (bf16*)ws;
  bf16* x5b       = (bf16*)(ws + 33554432ULL);
  bf16* x7b       = (bf16*)(ws + 67108864ULL);
  float* parts    = (float*)(ws + 234881024ULL);
  u8*   wf3       = (u8*)(ws + 234913792ULL);
  u8*   wf5       = (u8*)(ws + 236093440ULL);
  u8*   wf7       = (u8*)(ws + 239370240ULL);
  bf16* wb1       = (bf16*)(ws + 245792768ULL);

  prep_w_kernel<<<dim3(2048), 256, 0, stream>>>(w3, w5, w7, w1,
      wq_st, wk_st, wv_st, wq_phy, wk_phy, wv_phy,
      wf3, wf5, wf7, wb1, wproj);
  xpose_in_kernel<<<dim3(64, 128), 256, 0, stream>>>(st, phy, Xt);

  for (int g = 0; g < 4; ++g) {
    proj_mfma<<<dim3(8, 128), 256, 0, stream>>>(Xt, wproj,
        bq_st, bk_st, bv_st, bq_phy, bk_phy, bv_phy, projchunk, g * 32);
    attn_mfma_kernel<<<dim3(32, 128), 64, 0, stream>>>(projchunk, st, phy,
        cA, cB, g * 32);
  }
  transpose_kernel<<<dim3(128, 128), 256, 0, stream>>>(cA, cB, cAT, cBT);
  to_fp8_kernel<<<dim3(16384), 256, 0, stream>>>(cAT, cBT, cAT8);

  conv_mfma<1><<<dim3(512), 256, 0, stream>>>(cAT, cBT, wb1, b1, x1b, parts + 6144);
  conv_mx<3><<<dim3(512), 256, 0, stream>>>(cAT8, wf3, x3b, parts);
  conv_mx<5><<<dim3(512), 256, 0, stream>>>(cAT8, wf5, x5b, parts + 2048);
  conv_mx<7><<<dim3(512), 256, 0, stream>>>(cAT8, wf7, x7b, parts + 4096);

  final_kernel<<<dim3(8, 128), 256, 0, stream>>>(x3b, x5b, x7b, x1b,
      parts, parts + 2048, parts + 4096, parts + 6144,
      g3, be3, g5, be5, g7, be7, g1, be1, (float*)d_out);
}

// Round 16
// 1419.781 us; speedup vs baseline: 1.6255x; 1.6255x over previous
//
#include <hip/hip_runtime.h>
#include <hip/hip_bf16.h>

typedef __hip_bfloat16 bf16;
typedef unsigned char u8;
typedef unsigned long long u64;
typedef __attribute__((ext_vector_type(8))) short short8;
typedef __attribute__((ext_vector_type(8))) int i32x8;
typedef __attribute__((ext_vector_type(16))) float f32x16;
#define DI __device__ __forceinline__

union BF8 { int4 v; short8 s; bf16 h[8]; };
union BF4 { u64 u; bf16 h[4]; };
union U32B { int4 v[2]; i32x8 w; };

// ws layout (bytes):
// phase A: Xt @0 | projchunk @67,108,864 | cA @117,440,512 | cB @184,549,376
//          wproj @218,103,808
// phase B: transpose -> cAT @0, cBT @67,108,864 (over dead Xt/projchunk)
//          to_fp8 (SEPARATE kernel; fusing into transpose races cA -- R14 NaN)
//          -> cAT8 @117,440,512 (over dead cA)
// phase C: conv1 -> x1 @184,549,376; conv3/5/7 (MX fp8) -> x3 @0,
//          x5 @33,554,432, x7 @67,108,864
// parts @234,881,024 (32 KB): conv3 @0, conv5 @+2048, conv7 @+4096, conv1 @+6144
// wf3 @234,913,792 | wf5 @236,093,440 | wf7 @239,370,240 | wb1 @245,792,768

DI u8 f32_fp8(float v) {
  return (u8)(__builtin_amdgcn_cvt_pk_fp8_f32(v, 0.f, 0, false) & 0xff);
}

// ---------------------------------------------------------------- weight prep
// MX layout for wf3/5/7 (x256): addr = (((tap*8+cc2)*2+g)*128+oc)*32 + o,
//   ic = (cc2*2+g)*32 + ((o>>3)&1)*16 + ((o>>4)&1)*8 + (o&7)   [matches cAT8]
__global__ __launch_bounds__(256) void prep_w_kernel(
    const float* __restrict__ w3, const float* __restrict__ w5,
    const float* __restrict__ w7, const float* __restrict__ w1,
    const float* __restrict__ wq_st, const float* __restrict__ wk_st,
    const float* __restrict__ wv_st, const float* __restrict__ wq_phy,
    const float* __restrict__ wk_phy, const float* __restrict__ wv_phy,
    u8* __restrict__ wf3, u8* __restrict__ wf5,
    u8* __restrict__ wf7, bf16* __restrict__ wb1, bf16* __restrict__ wp)
{
  const int N3 = 9 * 65536, N5 = 25 * 65536, N7 = 49 * 65536, N1 = 65536;
  const int NP = 6 * 16384;
  const int total = N3 + N5 + N7 + N1 + NP;
  for (int i = blockIdx.x * 256 + threadIdx.x; i < total; i += gridDim.x * 256) {
    if (i < N3 + N5 + N7) {
      const float* w; int k; int taps;
      u8* dst;
      if (i < N3)           { w = w3; k = i;            taps = 9;  dst = wf3; }
      else if (i < N3 + N5) { w = w5; k = i - N3;       taps = 25; dst = wf5; }
      else                  { w = w7; k = i - N3 - N5;  taps = 49; dst = wf7; }
      int tap = k >> 16, rem = k & 65535;
      int cc2 = rem >> 13, r2 = rem & 8191;
      int g = r2 >> 12, r3 = r2 & 4095;
      int oc = r3 >> 5, o = r3 & 31;
      int ic = (cc2 * 2 + g) * 32 + ((o >> 3) & 1) * 16 + ((o >> 4) & 1) * 8 + (o & 7);
      dst[k] = f32_fp8(w[(size_t)(oc * 512 + ic) * taps + tap] * 256.0f);
    } else if (i < N3 + N5 + N7 + N1) {
      int k = i - N3 - N5 - N7;
      int icg = k >> 10, oc = (k >> 3) & 127, j = k & 7;
      wb1[k] = __float2bfloat16(w1[(size_t)oc * 512 + icg * 8 + j]);
    } else {
      int k = i - N3 - N5 - N7 - N1;
      int m = k >> 14, r = k & 16383;
      float v;
      switch (m) {
        case 0: v = wq_st[r]; break;
        case 1: v = wk_st[r]; break;
        case 2: v = wv_st[r]; break;
        case 3: v = wq_phy[r]; break;
        case 4: v = wk_phy[r]; break;
        default: v = wv_phy[r]; break;
      }
      wp[k] = __float2bfloat16(v);
    }
  }
}

// ---------------------------------------------------------------- input transpose
__global__ __launch_bounds__(256) void xpose_in_kernel(
    const float* __restrict__ st, const float* __restrict__ phy,
    bf16* __restrict__ Xt)
{
  __shared__ __align__(16) short Tb[64 * 72];
  const int x = blockIdx.x, b = blockIdx.y;
  const int t = x >> 5, rem = x & 31;
  const int ict = rem >> 4, post = rem & 15;
  const int ic0 = ict * 64, pos0 = post * 64;
  const int tid = threadIdx.x;
  const int rowi = tid >> 2, sub = tid & 3;
  const float* X = t ? phy : st;

  const float* src = X + ((size_t)b * 128 + ic0 + rowi) * 1024 + pos0 + sub * 16;
  #pragma unroll
  for (int q = 0; q < 4; ++q) {
    float4 v = *(const float4*)(src + q * 4);
    BF4 pk;
    pk.h[0] = __float2bfloat16(v.x); pk.h[1] = __float2bfloat16(v.y);
    pk.h[2] = __float2bfloat16(v.z); pk.h[3] = __float2bfloat16(v.w);
    *(u64*)&Tb[rowi * 72 + sub * 16 + q * 4] = pk.u;
  }
  __syncthreads();
  short tmp[16];
  #pragma unroll
  for (int j = 0; j < 16; ++j) tmp[j] = Tb[(sub * 16 + j) * 72 + rowi];
  bf16* dst = Xt + (((size_t)t * 128 + b) * 1024 + pos0 + rowi) * 128 + ic0 + sub * 16;
  *(int4*)dst       = ((int4*)tmp)[0];
  *(int4*)(dst + 8) = ((int4*)tmp)[1];
}

// ---------------------------------------------------------------- MFMA projections
__global__ __launch_bounds__(256) void proj_mfma(
    const bf16* __restrict__ Xt, const bf16* __restrict__ wproj,
    const float* __restrict__ b0, const float* __restrict__ b1,
    const float* __restrict__ b2, const float* __restrict__ b3,
    const float* __restrict__ b4, const float* __restrict__ b5,
    bf16* __restrict__ pc, int cb)
{
  const int pt = blockIdx.x, b = blockIdx.y;
  const int tid = threadIdx.x, wave = tid >> 6, lane = tid & 63;
  const int col = lane & 31, kg = lane >> 5;
  const int pos = pt * 128 + wave * 32 + col;

  f32x16 acc[6];
  #pragma unroll
  for (int m = 0; m < 6; ++m)
    #pragma unroll
    for (int e = 0; e < 16; ++e) acc[m][e] = 0.f;

  const bf16* xst = Xt + ((size_t)b * 1024 + pos) * 128 + kg * 8;
  const bf16* xph = xst + (size_t)128 * 1024 * 128;
  const bf16* wl = wproj + (size_t)(cb + col) * 128 + kg * 8;

  #pragma unroll
  for (int kst = 0; kst < 8; ++kst) {
    short8 bst = *(const short8*)&xst[kst * 16];
    short8 bph = *(const short8*)&xph[kst * 16];
    #pragma unroll
    for (int m = 0; m < 6; ++m) {
      BF8 a; a.v = *(const int4*)&wl[(size_t)m * 16384 + kst * 16];
      acc[m] = __builtin_amdgcn_mfma_f32_32x32x16_bf16(a.s, m < 3 ? bst : bph, acc[m], 0, 0, 0);
    }
  }
  const float* biases[6] = { b0, b1, b2, b3, b4, b5 };
  #pragma unroll
  for (int m = 0; m < 6; ++m) {
    #pragma unroll
    for (int r = 0; r < 16; ++r) {
      const int ocl = (r & 3) + 8 * (r >> 2) + 4 * kg;
      float v = acc[m][r] + biases[m][cb + ocl];
      pc[(((size_t)m * 128 + b) * 32 + ocl) * 1024 + pos] = __float2bfloat16(v);
    }
  }
}

// ---------------------------------------------------------------- MFMA attention
DI void softmax_rows(float p[16])
{
  #pragma unroll
  for (int r = 0; r < 16; ++r) {
    float m = p[r];
    m = fmaxf(m, __shfl_xor(m, 1));
    m = fmaxf(m, __shfl_xor(m, 2));
    m = fmaxf(m, __shfl_xor(m, 4));
    m = fmaxf(m, __shfl_xor(m, 8));
    m = fmaxf(m, __shfl_xor(m, 16));
    float e = __expf(p[r] - m);
    float s = e;
    s += __shfl_xor(s, 1); s += __shfl_xor(s, 2); s += __shfl_xor(s, 4);
    s += __shfl_xor(s, 8); s += __shfl_xor(s, 16);
    p[r] = __fdividef(e, s);
  }
}

template<bool U8OUT>
DI void attn_one_mfma(const BF8& qa0, const BF8& qa1,
                      const bf16* __restrict__ KT, const bf16* __restrict__ VT,
                      bf16* __restrict__ P,
                      const float* __restrict__ resid, void* outp, int lane)
{
  const int col = lane & 31, kg = lane >> 5;
  f32x16 acc;
  #pragma unroll
  for (int e = 0; e < 16; ++e) acc[e] = 0.f;
  BF8 kb0, kb1;
  kb0.v = *(const int4*)&KT[col * 40 + kg * 8];
  kb1.v = *(const int4*)&KT[col * 40 + 16 + kg * 8];
  acc = __builtin_amdgcn_mfma_f32_32x32x16_bf16(qa0.s, kb0.s, acc, 0, 0, 0);
  acc = __builtin_amdgcn_mfma_f32_32x32x16_bf16(qa1.s, kb1.s, acc, 0, 0, 0);
  float p[16];
  #pragma unroll
  for (int r = 0; r < 16; ++r) p[r] = acc[r];
  softmax_rows(p);
  __syncthreads();
  #pragma unroll
  for (int r = 0; r < 16; ++r) {
    int row = (r & 3) + 8 * (r >> 2) + 4 * kg;
    P[row * 40 + col] = __float2bfloat16(p[r]);
  }
  __syncthreads();
  BF8 pa0, pa1, vb0, vb1;
  pa0.v = *(const int4*)&P[col * 40 + kg * 8];
  pa1.v = *(const int4*)&P[col * 40 + 16 + kg * 8];
  vb0.v = *(const int4*)&VT[col * 40 + kg * 8];
  vb1.v = *(const int4*)&VT[col * 40 + 16 + kg * 8];
  #pragma unroll
  for (int e = 0; e < 16; ++e) acc[e] = 0.f;
  acc = __builtin_amdgcn_mfma_f32_32x32x16_bf16(pa0.s, vb0.s, acc, 0, 0, 0);
  acc = __builtin_amdgcn_mfma_f32_32x32x16_bf16(pa1.s, vb1.s, acc, 0, 0, 0);
  #pragma unroll
  for (int r = 0; r < 16; ++r) p[r] = acc[r];
  softmax_rows(p);
  if constexpr (!U8OUT) {
    bf16* op = (bf16*)outp;
    #pragma unroll
    for (int r = 0; r < 16; ++r) {
      int row = (r & 3) + 8 * (r >> 2) + 4 * kg;
      int off = row * 32 + col;
      op[off] = __float2bfloat16(p[r] + resid[off]);
    }
  } else {
    u8* op = (u8*)outp;
    #pragma unroll
    for (int r = 0; r < 16; ++r) {
      int row = (r & 3) + 8 * (r >> 2) + 4 * kg;
      op[row * 32 + col] = (u8)fminf(p[r] * 256.f + 0.5f, 255.f);
    }
  }
}

__global__ __launch_bounds__(64) void attn_mfma_kernel(
    const bf16* __restrict__ pc,
    const float* __restrict__ st, const float* __restrict__ phy,
    bf16* __restrict__ cA, u8* __restrict__ cB, int cb)
{
  __shared__ __align__(16) bf16 KTst[32 * 40], VTst[32 * 40];
  __shared__ __align__(16) bf16 KTph[32 * 40], VTph[32 * 40];
  __shared__ __align__(16) bf16 P[32 * 40];
  const int cl = blockIdx.x, b = blockIdx.y;
  const int c = cb + cl;
  const int lane = threadIdx.x;
  const size_t mstride = (size_t)128 * 32 * 1024;
  const bf16* p0 = pc + ((size_t)b * 32 + cl) * 1024;
  const size_t bc = ((size_t)b * 128 + c) * 1024;

  {
    const int w = lane >> 1, k0 = (lane & 1) * 16;
    const int off = w * 32 + k0;
    bf16* dsts[4] = { KTst, VTst, KTph, VTph };
    const int ms[4] = { 1, 2, 4, 5 };
    #pragma unroll
    for (int t = 0; t < 4; ++t) {
      BF8 r0, r1;
      r0.v = *(const int4*)&p0[(size_t)ms[t] * mstride + off];
      r1.v = *(const int4*)&p0[(size_t)ms[t] * mstride + off + 8];
      #pragma unroll
      for (int j = 0; j < 8; ++j) {
        dsts[t][(k0 + j) * 40 + w]     = r0.h[j];
        dsts[t][(k0 + 8 + j) * 40 + w] = r1.h[j];
      }
    }
  }
  const int col = lane & 31, kg = lane >> 5;
  BF8 qst0, qst1, qph0, qph1;
  qst0.v = *(const int4*)&p0[col * 32 + kg * 8];
  qst1.v = *(const int4*)&p0[col * 32 + 16 + kg * 8];
  qph0.v = *(const int4*)&p0[3 * mstride + col * 32 + kg * 8];
  qph1.v = *(const int4*)&p0[3 * mstride + col * 32 + 16 + kg * 8];
  __syncthreads();

  bf16* aA = cA + (size_t)b * 256 * 1024 + (size_t)c * 1024;
  u8*   aB = cB + (size_t)b * 256 * 1024 + (size_t)c * 1024;
  attn_one_mfma<false>(qst0, qst1, KTst, VTst, P, st + bc,  aA,          lane);
  attn_one_mfma<false>(qph0, qph1, KTph, VTph, P, phy + bc, aA + 131072, lane);
  attn_one_mfma<true >(qph0, qph1, KTst, VTst, P, nullptr,  aB,          lane);
  attn_one_mfma<true >(qst0, qst1, KTph, VTph, P, nullptr,  aB + 131072, lane);
}

// ---------------------------------------------------------------- concat transpose
__global__ __launch_bounds__(256) void transpose_kernel(
    const bf16* __restrict__ cA, const u8* __restrict__ cB,
    bf16* __restrict__ cAT, u8* __restrict__ cBT)
{
  __shared__ __align__(16) short Tb[64 * 72];
  __shared__ __align__(16) u8 T8[64 * 80];
  const int x = blockIdx.x, b = blockIdx.y;
  const int cht = x >> 4, post = x & 15;
  const int pos0 = post * 64;
  const int tid = threadIdx.x;
  const int rowi = tid >> 2, sub = tid & 3;

  if (cht < 4) {
    const int ch0 = cht * 64;
    const bf16* src = cA + ((size_t)b * 256 + ch0 + rowi) * 1024 + pos0 + sub * 16;
    *(int4*)&Tb[rowi * 72 + sub * 16]     = *(const int4*)src;
    *(int4*)&Tb[rowi * 72 + sub * 16 + 8] = *(const int4*)(src + 8);
    __syncthreads();
    short tmp[16];
    #pragma unroll
    for (int j = 0; j < 16; ++j) tmp[j] = Tb[(sub * 16 + j) * 72 + rowi];
    bf16* dst = cAT + ((size_t)b * 1024 + pos0 + rowi) * 256 + ch0 + sub * 16;
    *(int4*)dst       = ((int4*)tmp)[0];
    *(int4*)(dst + 8) = ((int4*)tmp)[1];
  } else {
    const int ch0 = (cht - 4) * 64;
    const u8* src = cB + ((size_t)b * 256 + ch0 + rowi) * 1024 + pos0 + sub * 16;
    *(int4*)&T8[rowi * 80 + sub * 16] = *(const int4*)src;
    __syncthreads();
    u8 tmp[16];
    #pragma unroll
    for (int j = 0; j < 16; ++j) tmp[j] = T8[(sub * 16 + j) * 80 + rowi];
    u8* dst = cBT + ((size_t)b * 1024 + pos0 + rowi) * 256 + ch0 + sub * 16;
    *(int4*)dst = *(int4*)tmp;
  }
}

// ---------------------------------------------------------------- fp8 conversion pass
__global__ __launch_bounds__(256) void to_fp8_kernel(
    const bf16* __restrict__ cAT, const u8* __restrict__ cBT,
    u8* __restrict__ cAT8)
{
  const int idx = blockIdx.x * 256 + threadIdx.x;
  const int g = idx & 31;
  const size_t bp = (size_t)(idx >> 5);
  const int c0 = g * 16;
  float v[16];
  if (c0 < 256) {
    BF8 lo, hi;
    lo.v = *(const int4*)&cAT[bp * 256 + c0];
    hi.v = *(const int4*)&cAT[bp * 256 + c0 + 8];
    #pragma unroll
    for (int j = 0; j < 8; ++j) {
      v[j]     = __bfloat162float(lo.h[j]) * 16.0f;
      v[8 + j] = __bfloat162float(hi.h[j]) * 16.0f;
    }
  } else {
    u64 raw0 = *(const u64*)&cBT[bp * 256 + (c0 - 256)];
    u64 raw1 = *(const u64*)&cBT[bp * 256 + (c0 - 256) + 8];
    #pragma unroll
    for (int j = 0; j < 8; ++j) {
      v[j]     = (float)((raw0 >> (8 * j)) & 255u) * 0.0625f;
      v[8 + j] = (float)((raw1 >> (8 * j)) & 255u) * 0.0625f;
    }
  }
  unsigned lo0 = (__builtin_amdgcn_cvt_pk_fp8_f32(v[0], v[1], 0, false) & 0xffff)
               | ((__builtin_amdgcn_cvt_pk_fp8_f32(v[2], v[3], 0, false) & 0xffff) << 16);
  unsigned hi0 = (__builtin_amdgcn_cvt_pk_fp8_f32(v[4], v[5], 0, false) & 0xffff)
               | ((__builtin_amdgcn_cvt_pk_fp8_f32(v[6], v[7], 0, false) & 0xffff) << 16);
  unsigned lo1 = (__builtin_amdgcn_cvt_pk_fp8_f32(v[8], v[9], 0, false) & 0xffff)
               | ((__builtin_amdgcn_cvt_pk_fp8_f32(v[10], v[11], 0, false) & 0xffff) << 16);
  unsigned hi1 = (__builtin_amdgcn_cvt_pk_fp8_f32(v[12], v[13], 0, false) & 0xffff)
               | ((__builtin_amdgcn_cvt_pk_fp8_f32(v[14], v[15], 0, false) & 0xffff) << 16);
  u64 run0 = (u64)lo0 | ((u64)hi0 << 32);
  u64 run1 = (u64)lo1 | ((u64)hi1 << 32);
  const int sp = (c0 >> 4) & 1;
  u8* d = cAT8 + bp * 512 + (c0 & ~31);
  *(u64*)(d + 8 * sp)      = run0;
  *(u64*)(d + 16 + 8 * sp) = run1;
}

// ---------------------------------------------------------------- staging (bf16)
template<int PCX, int NIT, int H0>
DI void stage_tile(const bf16* cAT, const u8* cBT, short* Xs,
                   int b, int r0, int ic0, int tid)
{
  for (int e = tid; e < NIT; e += 256) {
    int i = e / (PCX * 4);
    int rem = e - i * (PCX * 4);
    int cx = rem >> 2, part = rem & 3;
    int ir = r0 - H0 + i, c = cx - H0;
    int4 val = make_int4(0, 0, 0, 0);
    if ((unsigned)ir < 32u && (unsigned)c < 32u) {
      size_t pbase = ((size_t)b * 1024 + ir * 32 + c) * 256;
      if (ic0 < 256) {
        val = *(const int4*)&cAT[pbase + ic0 + part * 8];
      } else {
        u64 u = *(const u64*)&cBT[pbase + (ic0 - 256) + part * 8];
        BF8 t;
        #pragma unroll
        for (int j = 0; j < 8; ++j)
          t.h[j] = __float2bfloat16((float)((u >> (8 * j)) & 255u) * 0.00390625f);
        val = t.v;
      }
    }
    *(int4*)&Xs[(i * PCX + cx) * 40 + part * 8] = val;
  }
}

// ---------------------------------------------------------------- bf16 MFMA conv (conv1)
template<int KS>
__global__ __launch_bounds__(256, 2) void conv_mfma(
    const bf16* __restrict__ cAT, const u8* __restrict__ cBT,
    const bf16* __restrict__ wt, const float* __restrict__ bias,
    bf16* __restrict__ xout, float* __restrict__ partials)
{
  constexpr int H0 = KS / 2;
  constexpr int PCX = 32 + 2 * H0;
  constexpr int ROWS = 16 + 2 * H0;
  constexpr int NIT = ROWS * PCX * 4;
  __shared__ __align__(16) short Xs[ROWS * PCX * 40];
  __shared__ float rs[256], rq[256];
  const int h = blockIdx.x;
  const int logical = (h & 7) * 64 + (h >> 3);
  const int b = logical >> 2, tix = logical & 3;
  const int ot = tix >> 1, rt = tix & 1;
  const int oc0 = ot * 64, r0 = rt * 16;
  const int tid = threadIdx.x;
  const int wv = tid >> 6, lane = tid & 63;
  const int col = lane & 31, kg = lane >> 5;

  f32x16 acc[2][4];
  #pragma unroll
  for (int i = 0; i < 2; ++i)
    #pragma unroll
    for (int j = 0; j < 4; ++j)
      #pragma unroll
      for (int e = 0; e < 16; ++e) acc[i][j][e] = 0.f;

  for (int cc = 0; cc < 16; ++cc) {
    const int ic0 = cc * 32;
    stage_tile<PCX, NIT, H0>(cAT, cBT, Xs, b, r0, ic0, tid);
    __syncthreads();

    #pragma unroll 1
    for (int ky = 0; ky < KS; ++ky) {
      #pragma unroll
      for (int kx = 0; kx < KS; ++kx) {
        const int tap = ky * KS + kx;
        BF8 a[2][2];
        #pragma unroll
        for (int ob = 0; ob < 2; ++ob)
          #pragma unroll
          for (int kt = 0; kt < 2; ++kt) {
            int icg = cc * 4 + kt * 2 + kg;
            a[ob][kt].v = *(const int4*)&wt[(((size_t)tap * 64 + icg) * 128 + oc0 + ob * 32 + col) * 8];
          }
        #pragma unroll
        for (int rr = 0; rr < 4; ++rr) {
          int entry = ((wv * 4 + rr + ky) * PCX + col + kx) * 40;
          #pragma unroll
          for (int kt = 0; kt < 2; ++kt) {
            short8 bf = *(const short8*)&Xs[entry + (kt * 2 + kg) * 8];
            acc[0][rr] = __builtin_amdgcn_mfma_f32_32x32x16_bf16(a[0][kt].s, bf, acc[0][rr], 0, 0, 0);
            acc[1][rr] = __builtin_amdgcn_mfma_f32_32x32x16_bf16(a[1][kt].s, bf, acc[1][rr], 0, 0, 0);
          }
        }
      }
    }
    __syncthreads();
  }

  float lsum = 0.f, lsq = 0.f;
  #pragma unroll
  for (int ob = 0; ob < 2; ++ob)
    #pragma unroll
    for (int rr = 0; rr < 4; ++rr) {
      const int row = r0 + wv * 4 + rr;
      #pragma unroll
      for (int r = 0; r < 16; ++r) {
        const int oc = oc0 + ob * 32 + (r & 3) + 8 * (r >> 2) + 4 * kg;
        float v = acc[ob][rr][r];
        if (bias) v += bias[oc];
        xout[((size_t)b * 128 + oc) * 1024 + row * 32 + col] = __float2bfloat16(v);
        lsum += v; lsq += v * v;
      }
    }
  rs[tid] = lsum; rq[tid] = lsq;
  __syncthreads();
  for (int s = 128; s > 0; s >>= 1) {
    if (tid < s) { rs[tid] += rs[tid + s]; rq[tid] += rq[tid + s]; }
    __syncthreads();
  }
  if (tid == 0) {
    partials[((size_t)b * 4 + tix) * 2]     = rs[0];
    partials[((size_t)b * 4 + tix) * 2 + 1] = rq[0];
  }
}

// ---------------------------------------------------------------- MX fp8 conv (KS=3,5,7)
// ob=4 x rr=2, 8-row tiles: 2 LDS entries read per tap (vs 4 in the R13
// ob=2 x rr=4 shape); A-loads are wave-uniform L1 broadcasts (TA pipe,
// parallel to LDS). __launch_bounds__(256,2): full 256-reg budget -- the
// (256,3) cap spilled acc to scratch (R15: WRITE_SIZE 282 MB, 924 us).
// 2 blocks/CU, LDS 42.6 KB @ KS=7. Grid 512, XCD-swizzled. Partials 4/batch.
template<int KS>
__global__ __launch_bounds__(256, 2) void conv_mx(
    const u8* __restrict__ cAT8, const u8* __restrict__ wf,
    bf16* __restrict__ xout, float* __restrict__ partials)
{
  constexpr int H0 = KS / 2;
  constexpr int PCX = 32 + 2 * H0;
  constexpr int ROWS = 8 + 2 * H0;
  constexpr int NIT = ROWS * PCX * 4;              // 16-B units
  __shared__ __align__(16) u8 Xs[ROWS * PCX * 80];
  __shared__ float rs[256], rq[256];
  const int h = blockIdx.x;
  const int logical = (h & 7) * 64 + (h >> 3);
  const int b = logical >> 2, rt = logical & 3;
  const int r0 = rt * 8;
  const int tid = threadIdx.x;
  const int wv = tid >> 6, lane = tid & 63;
  const int col = lane & 31, g = lane >> 5;

  f32x16 acc[4][2];
  #pragma unroll
  for (int i = 0; i < 4; ++i)
    #pragma unroll
    for (int j = 0; j < 2; ++j)
      #pragma unroll
      for (int e = 0; e < 16; ++e) acc[i][j][e] = 0.f;

  for (int cc2 = 0; cc2 < 8; ++cc2) {
    for (int e = tid; e < NIT; e += 256) {
      int entry = e >> 2, hf = e & 3;
      int i = entry / PCX, cx = entry - i * PCX;
      int ir = r0 - H0 + i, c = cx - H0;
      int4 val = make_int4(0, 0, 0, 0);
      if ((unsigned)ir < 32u && (unsigned)c < 32u)
        val = *(const int4*)&cAT8[((size_t)b * 1024 + ir * 32 + c) * 512 + cc2 * 64 + hf * 16];
      *(int4*)&Xs[entry * 80 + hf * 16] = val;
    }
    __syncthreads();

    #pragma unroll 1
    for (int ky = 0; ky < KS; ++ky) {
      #pragma unroll
      for (int kx = 0; kx < KS; ++kx) {
        const int tap = ky * KS + kx;
        const size_t wbase = (((size_t)tap * 8 + cc2) * 2 + g) * 128;
        U32B bf0, bf1;
        {
          const int e0 = ((wv * 2 + 0 + ky) * PCX + col + kx) * 80 + g * 32;
          const int e1 = ((wv * 2 + 1 + ky) * PCX + col + kx) * 80 + g * 32;
          bf0.v[0] = *(const int4*)&Xs[e0];
          bf0.v[1] = *(const int4*)&Xs[e0 + 16];
          bf1.v[0] = *(const int4*)&Xs[e1];
          bf1.v[1] = *(const int4*)&Xs[e1 + 16];
        }
        #pragma unroll
        for (int ob = 0; ob < 4; ++ob) {
          U32B a;
          a.v[0] = *(const int4*)&wf[(wbase + ob * 32 + col) * 32];
          a.v[1] = *(const int4*)&wf[(wbase + ob * 32 + col) * 32 + 16];
          acc[ob][0] = __builtin_amdgcn_mfma_scale_f32_32x32x64_f8f6f4(
              a.w, bf0.w, acc[ob][0], 0, 0, 0, 0x7f7f7f7f, 0, 0x7f7f7f7f);
          acc[ob][1] = __builtin_amdgcn_mfma_scale_f32_32x32x64_f8f6f4(
              a.w, bf1.w, acc[ob][1], 0, 0, 0, 0x7f7f7f7f, 0, 0x7f7f7f7f);
        }
      }
    }
    __syncthreads();
  }

  float lsum = 0.f, lsq = 0.f;
  #pragma unroll
  for (int ob = 0; ob < 4; ++ob)
    #pragma unroll
    for (int rr = 0; rr < 2; ++rr) {
      const int row = r0 + wv * 2 + rr;
      #pragma unroll
      for (int r = 0; r < 16; ++r) {
        const int oc = ob * 32 + (r & 3) + 8 * (r >> 2) + 4 * g;
        float v = acc[ob][rr][r] * (1.0f / 4096.0f);
        xout[((size_t)b * 128 + oc) * 1024 + row * 32 + col] = __float2bfloat16(v);
        lsum += v; lsq += v * v;
      }
    }
  rs[tid] = lsum; rq[tid] = lsq;
  __syncthreads();
  for (int s = 128; s > 0; s >>= 1) {
    if (tid < s) { rs[tid] += rs[tid + s]; rq[tid] += rq[tid + s]; }
    __syncthreads();
  }
  if (tid == 0) {
    partials[((size_t)b * 4 + rt) * 2]     = rs[0];
    partials[((size_t)b * 4 + rt) * 2 + 1] = rq[0];
  }
}

// ---------------------------------------------------------------- LN + combine (4 partials each)
__global__ __launch_bounds__(256) void final_kernel(
    const bf16* __restrict__ x3, const bf16* __restrict__ x5,
    const bf16* __restrict__ x7, const bf16* __restrict__ x1c,
    const float* __restrict__ p3, const float* __restrict__ p5,
    const float* __restrict__ p7, const float* __restrict__ p1,
    const float* __restrict__ g3, const float* __restrict__ be3,
    const float* __restrict__ g5, const float* __restrict__ be5,
    const float* __restrict__ g7, const float* __restrict__ be7,
    const float* __restrict__ g1, const float* __restrict__ be1,
    float* __restrict__ out)
{
  const int blk = blockIdx.x, b = blockIdx.y, tid = threadIdx.x;
  float s3 = 0, q3 = 0, s5 = 0, q5 = 0, s7 = 0, q7 = 0, s1 = 0, q1 = 0;
  #pragma unroll
  for (int i = 0; i < 4; ++i) {
    int o = (b * 4 + i) * 2;
    s3 += p3[o]; q3 += p3[o + 1];
    s5 += p5[o]; q5 += p5[o + 1];
    s7 += p7[o]; q7 += p7[o + 1];
    s1 += p1[o]; q1 += p1[o + 1];
  }
  const float inv = 1.0f / 131072.0f;
  float mu3 = s3 * inv, r3 = rsqrtf(fmaxf(q3 * inv - mu3 * mu3, 0.f) + 1e-5f);
  float mu5 = s5 * inv, r5 = rsqrtf(fmaxf(q5 * inv - mu5 * mu5, 0.f) + 1e-5f);
  float mu7 = s7 * inv, r7 = rsqrtf(fmaxf(q7 * inv - mu7 * mu7, 0.f) + 1e-5f);
  float mu1 = s1 * inv, r1 = rsqrtf(fmaxf(q1 * inv - mu1 * mu1, 0.f) + 1e-5f);
  const size_t bb = (size_t)b * 131072;
  for (int it = 0; it < 8; ++it) {
    int e0 = (it * 2048 + blk * 256 + tid) * 8;
    BF8 a3, a5, a7, a1;
    a3.v = *(const int4*)&x3[bb + e0];
    a5.v = *(const int4*)&x5[bb + e0];
    a7.v = *(const int4*)&x7[bb + e0];
    a1.v = *(const int4*)&x1c[bb + e0];
    float G3[8], B3[8], G5[8], B5[8], G7[8], B7[8], G1[8], B1[8];
    *(float4*)&G3[0] = *(const float4*)&g3[e0];  *(float4*)&G3[4] = *(const float4*)&g3[e0 + 4];
    *(float4*)&B3[0] = *(const float4*)&be3[e0]; *(float4*)&B3[4] = *(const float4*)&be3[e0 + 4];
    *(float4*)&G5[0] = *(const float4*)&g5[e0];  *(float4*)&G5[4] = *(const float4*)&g5[e0 + 4];
    *(float4*)&B5[0] = *(const float4*)&be5[e0]; *(float4*)&B5[4] = *(const float4*)&be5[e0 + 4];
    *(float4*)&G7[0] = *(const float4*)&g7[e0];  *(float4*)&G7[4] = *(const float4*)&g7[e0 + 4];
    *(float4*)&B7[0] = *(const float4*)&be7[e0]; *(float4*)&B7[4] = *(const float4*)&be7[e0 + 4];
    *(float4*)&G1[0] = *(const float4*)&g1[e0];  *(float4*)&G1[4] = *(const float4*)&g1[e0 + 4];
    *(float4*)&B1[0] = *(const float4*)&be1[e0]; *(float4*)&B1[4] = *(const float4*)&be1[e0 + 4];
    float res[8];
    #pragma unroll
    for (int j = 0; j < 8; ++j) {
      float v3 = (__bfloat162float(a3.h[j]) - mu3) * r3 * G3[j] + B3[j];
      float v5 = (__bfloat162float(a5.h[j]) - mu5) * r5 * G5[j] + B5[j];
      float v7 = (__bfloat162float(a7.h[j]) - mu7) * r7 * G7[j] + B7[j];
      float m = (v3 + v5 + v7) * (1.0f / 3.0f);
      float sg = 1.0f / (1.0f + __expf(-m));
      float v1 = (__bfloat162float(a1.h[j]) - mu1) * r1 * G1[j] + B1[j];
      res[j] = sg + v1;
    }
    *(float4*)&out[bb + e0]     = make_float4(res[0], res[1], res[2], res[3]);
    *(float4*)&out[bb + e0 + 4] = make_float4(res[4], res[5], res[6], res[7]);
  }
}

// ---------------------------------------------------------------- launch
extern "C" void kernel_launch(void* const* d_in, const int* in_sizes, int n_in,
                              void* d_out, int out_size, void* d_ws, size_t ws_size,
                              hipStream_t stream)
{
  (void)in_sizes; (void)n_in; (void)out_size; (void)ws_size;
  const float* st     = (const float*)d_in[0];
  const float* phy    = (const float*)d_in[1];
  const float* wq_st  = (const float*)d_in[2];
  const float* bq_st  = (const float*)d_in[3];
  const float* wk_st  = (const float*)d_in[4];
  const float* bk_st  = (const float*)d_in[5];
  const float* wv_st  = (const float*)d_in[6];
  const float* bv_st  = (const float*)d_in[7];
  const float* wq_phy = (const float*)d_in[8];
  const float* bq_phy = (const float*)d_in[9];
  const float* wk_phy = (const float*)d_in[10];
  const float* bk_phy = (const float*)d_in[11];
  const float* wv_phy = (const float*)d_in[12];
  const float* bv_phy = (const float*)d_in[13];
  const float* w3  = (const float*)d_in[14];
  const float* g3  = (const float*)d_in[15];
  const float* be3 = (const float*)d_in[16];
  const float* w5  = (const float*)d_in[17];
  const float* g5  = (const float*)d_in[18];
  const float* be5 = (const float*)d_in[19];
  const float* w7  = (const float*)d_in[20];
  const float* g7  = (const float*)d_in[21];
  const float* be7 = (const float*)d_in[22];
  const float* w1  = (const float*)d_in[23];
  const float* g1  = (const float*)d_in[24];
  const float* be1 = (const float*)d_in[25];
  const float* b1  = (const float*)d_in[26];

  char* ws = (char*)d_ws;
  // phase A
  bf16* Xt        = (bf16*)ws;
  bf16* projchunk = (bf16*)(ws + 67108864ULL);
  bf16* cA        = (bf16*)(ws + 117440512ULL);
  u8*   cB        = (u8*)(ws + 184549376ULL);
  bf16* wproj     = (bf16*)(ws + 218103808ULL);
  // phase B/C
  bf16* cAT       = (bf16*)ws;
  u8*   cBT       = (u8*)(ws + 67108864ULL);
  u8*   cAT8      = (u8*)(ws + 117440512ULL);
  bf16* x1b       = (bf16*)(ws + 184549376ULL);
  bf16* x3b       = (bf16*)ws;
  bf16* x5b       = (bf16*)(ws + 33554432ULL);
  bf16* x7b       = (bf16*)(ws + 67108864ULL);
  float* parts    = (float*)(ws + 234881024ULL);
  u8*   wf3       = (u8*)(ws + 234913792ULL);
  u8*   wf5       = (u8*)(ws + 236093440ULL);
  u8*   wf7       = (u8*)(ws + 239370240ULL);
  bf16* wb1       = (bf16*)(ws + 245792768ULL);

  prep_w_kernel<<<dim3(2048), 256, 0, stream>>>(w3, w5, w7, w1,
      wq_st, wk_st, wv_st, wq_phy, wk_phy, wv_phy,
      wf3, wf5, wf7, wb1, wproj);
  xpose_in_kernel<<<dim3(64, 128), 256, 0, stream>>>(st, phy, Xt);

  for (int g = 0; g < 4; ++g) {
    proj_mfma<<<dim3(8, 128), 256, 0, stream>>>(Xt, wproj,
        bq_st, bk_st, bv_st, bq_phy, bk_phy, bv_phy, projchunk, g * 32);
    attn_mfma_kernel<<<dim3(32, 128), 64, 0, stream>>>(projchunk, st, phy,
        cA, cB, g * 32);
  }
  transpose_kernel<<<dim3(128, 128), 256, 0, stream>>>(cA, cB, cAT, cBT);
  to_fp8_kernel<<<dim3(16384), 256, 0, stream>>>(cAT, cBT, cAT8);

  conv_mfma<1><<<dim3(512), 256, 0, stream>>>(cAT, cBT, wb1, b1, x1b, parts + 6144);
  conv_mx<3><<<dim3(512), 256, 0, stream>>>(cAT8, wf3, x3b, parts);
  conv_mx<5><<<dim3(512), 256, 0, stream>>>(cAT8, wf5, x5b, parts + 2048);
  conv_mx<7><<<dim3(512), 256, 0, stream>>>(cAT8, wf7, x7b, parts + 4096);

  final_kernel<<<dim3(8, 128), 256, 0, stream>>>(x3b, x5b, x7b, x1b,
      parts, parts + 2048, parts + 4096, parts + 6144,
      g3, be3, g5, be5, g7, be7, g1, be1, (float*)d_out);
}

// Round 17
// 1232.829 us; speedup vs baseline: 1.8720x; 1.1516x over previous
//
#include <hip/hip_runtime.h>
#include <hip/hip_bf16.h>

typedef __hip_bfloat16 bf16;
typedef unsigned char u8;
typedef unsigned long long u64;
typedef __attribute__((ext_vector_type(8))) short short8;
typedef __attribute__((ext_vector_type(8))) int i32x8;
typedef __attribute__((ext_vector_type(16))) float f32x16;
#define DI __device__ __forceinline__

union BF8 { int4 v; short8 s; bf16 h[8]; };
union BF4 { u64 u; bf16 h[4]; };
union U32B { int4 v[2]; i32x8 w; };

// ws layout (bytes):
// phase A: Xt @0 | projchunk @67,108,864 | cA @117,440,512 | cB @184,549,376
//          wproj @218,103,808
// phase B: transpose -> cAT @0, cBT @67,108,864 (over dead Xt/projchunk)
//          to_fp8 (SEPARATE kernel; fusing into transpose races cA -- R14 NaN)
//          -> cAT8 @117,440,512 (over dead cA)
// phase C: conv1 -> x1 @184,549,376; conv3/5/7 (MX fp8) -> x3 @0,
//          x5 @33,554,432, x7 @67,108,864
// parts @234,881,024 (32 KB): conv3 @0, conv5 @+2048, conv7 @+4096, conv1 @+6144
// wf3 @234,913,792 | wf5 @236,093,440 | wf7 @239,370,240 | wb1 @245,792,768
//
// conv_mx shape history: ob=2 x rr=4 16-row (R13: 298us, MfmaUtil 64%) BEATS
// ob=4 x rr=2 8-row (R16: 400us, 44% -- per-lane A-loads double L1 demand) and
// (256,3) bounds (R15: acc spill, 924us). Keep R13's shape.

DI u8 f32_fp8(float v) {
  return (u8)(__builtin_amdgcn_cvt_pk_fp8_f32(v, 0.f, 0, false) & 0xff);
}

// ---------------------------------------------------------------- weight prep
// MX layout for wf3/5/7 (x256): addr = (((tap*8+cc2)*2+g)*128+oc)*32 + o,
//   ic = (cc2*2+g)*32 + ((o>>3)&1)*16 + ((o>>4)&1)*8 + (o&7)   [matches cAT8]
__global__ __launch_bounds__(256) void prep_w_kernel(
    const float* __restrict__ w3, const float* __restrict__ w5,
    const float* __restrict__ w7, const float* __restrict__ w1,
    const float* __restrict__ wq_st, const float* __restrict__ wk_st,
    const float* __restrict__ wv_st, const float* __restrict__ wq_phy,
    const float* __restrict__ wk_phy, const float* __restrict__ wv_phy,
    u8* __restrict__ wf3, u8* __restrict__ wf5,
    u8* __restrict__ wf7, bf16* __restrict__ wb1, bf16* __restrict__ wp)
{
  const int N3 = 9 * 65536, N5 = 25 * 65536, N7 = 49 * 65536, N1 = 65536;
  const int NP = 6 * 16384;
  const int total = N3 + N5 + N7 + N1 + NP;
  for (int i = blockIdx.x * 256 + threadIdx.x; i < total; i += gridDim.x * 256) {
    if (i < N3 + N5 + N7) {
      const float* w; int k; int taps;
      u8* dst;
      if (i < N3)           { w = w3; k = i;            taps = 9;  dst = wf3; }
      else if (i < N3 + N5) { w = w5; k = i - N3;       taps = 25; dst = wf5; }
      else                  { w = w7; k = i - N3 - N5;  taps = 49; dst = wf7; }
      int tap = k >> 16, rem = k & 65535;
      int cc2 = rem >> 13, r2 = rem & 8191;
      int g = r2 >> 12, r3 = r2 & 4095;
      int oc = r3 >> 5, o = r3 & 31;
      int ic = (cc2 * 2 + g) * 32 + ((o >> 3) & 1) * 16 + ((o >> 4) & 1) * 8 + (o & 7);
      dst[k] = f32_fp8(w[(size_t)(oc * 512 + ic) * taps + tap] * 256.0f);
    } else if (i < N3 + N5 + N7 + N1) {
      int k = i - N3 - N5 - N7;
      int icg = k >> 10, oc = (k >> 3) & 127, j = k & 7;
      wb1[k] = __float2bfloat16(w1[(size_t)oc * 512 + icg * 8 + j]);
    } else {
      int k = i - N3 - N5 - N7 - N1;
      int m = k >> 14, r = k & 16383;
      float v;
      switch (m) {
        case 0: v = wq_st[r]; break;
        case 1: v = wk_st[r]; break;
        case 2: v = wv_st[r]; break;
        case 3: v = wq_phy[r]; break;
        case 4: v = wk_phy[r]; break;
        default: v = wv_phy[r]; break;
      }
      wp[k] = __float2bfloat16(v);
    }
  }
}

// ---------------------------------------------------------------- input transpose
__global__ __launch_bounds__(256) void xpose_in_kernel(
    const float* __restrict__ st, const float* __restrict__ phy,
    bf16* __restrict__ Xt)
{
  __shared__ __align__(16) short Tb[64 * 72];
  const int x = blockIdx.x, b = blockIdx.y;
  const int t = x >> 5, rem = x & 31;
  const int ict = rem >> 4, post = rem & 15;
  const int ic0 = ict * 64, pos0 = post * 64;
  const int tid = threadIdx.x;
  const int rowi = tid >> 2, sub = tid & 3;
  const float* X = t ? phy : st;

  const float* src = X + ((size_t)b * 128 + ic0 + rowi) * 1024 + pos0 + sub * 16;
  #pragma unroll
  for (int q = 0; q < 4; ++q) {
    float4 v = *(const float4*)(src + q * 4);
    BF4 pk;
    pk.h[0] = __float2bfloat16(v.x); pk.h[1] = __float2bfloat16(v.y);
    pk.h[2] = __float2bfloat16(v.z); pk.h[3] = __float2bfloat16(v.w);
    *(u64*)&Tb[rowi * 72 + sub * 16 + q * 4] = pk.u;
  }
  __syncthreads();
  short tmp[16];
  #pragma unroll
  for (int j = 0; j < 16; ++j) tmp[j] = Tb[(sub * 16 + j) * 72 + rowi];
  bf16* dst = Xt + (((size_t)t * 128 + b) * 1024 + pos0 + rowi) * 128 + ic0 + sub * 16;
  *(int4*)dst       = ((int4*)tmp)[0];
  *(int4*)(dst + 8) = ((int4*)tmp)[1];
}

// ---------------------------------------------------------------- MFMA projections
__global__ __launch_bounds__(256) void proj_mfma(
    const bf16* __restrict__ Xt, const bf16* __restrict__ wproj,
    const float* __restrict__ b0, const float* __restrict__ b1,
    const float* __restrict__ b2, const float* __restrict__ b3,
    const float* __restrict__ b4, const float* __restrict__ b5,
    bf16* __restrict__ pc, int cb)
{
  const int pt = blockIdx.x, b = blockIdx.y;
  const int tid = threadIdx.x, wave = tid >> 6, lane = tid & 63;
  const int col = lane & 31, kg = lane >> 5;
  const int pos = pt * 128 + wave * 32 + col;

  f32x16 acc[6];
  #pragma unroll
  for (int m = 0; m < 6; ++m)
    #pragma unroll
    for (int e = 0; e < 16; ++e) acc[m][e] = 0.f;

  const bf16* xst = Xt + ((size_t)b * 1024 + pos) * 128 + kg * 8;
  const bf16* xph = xst + (size_t)128 * 1024 * 128;
  const bf16* wl = wproj + (size_t)(cb + col) * 128 + kg * 8;

  #pragma unroll
  for (int kst = 0; kst < 8; ++kst) {
    short8 bst = *(const short8*)&xst[kst * 16];
    short8 bph = *(const short8*)&xph[kst * 16];
    #pragma unroll
    for (int m = 0; m < 6; ++m) {
      BF8 a; a.v = *(const int4*)&wl[(size_t)m * 16384 + kst * 16];
      acc[m] = __builtin_amdgcn_mfma_f32_32x32x16_bf16(a.s, m < 3 ? bst : bph, acc[m], 0, 0, 0);
    }
  }
  const float* biases[6] = { b0, b1, b2, b3, b4, b5 };
  #pragma unroll
  for (int m = 0; m < 6; ++m) {
    #pragma unroll
    for (int r = 0; r < 16; ++r) {
      const int ocl = (r & 3) + 8 * (r >> 2) + 4 * kg;
      float v = acc[m][r] + biases[m][cb + ocl];
      pc[(((size_t)m * 128 + b) * 32 + ocl) * 1024 + pos] = __float2bfloat16(v);
    }
  }
}

// ---------------------------------------------------------------- MFMA attention
DI void softmax_rows(float p[16])
{
  #pragma unroll
  for (int r = 0; r < 16; ++r) {
    float m = p[r];
    m = fmaxf(m, __shfl_xor(m, 1));
    m = fmaxf(m, __shfl_xor(m, 2));
    m = fmaxf(m, __shfl_xor(m, 4));
    m = fmaxf(m, __shfl_xor(m, 8));
    m = fmaxf(m, __shfl_xor(m, 16));
    float e = __expf(p[r] - m);
    float s = e;
    s += __shfl_xor(s, 1); s += __shfl_xor(s, 2); s += __shfl_xor(s, 4);
    s += __shfl_xor(s, 8); s += __shfl_xor(s, 16);
    p[r] = __fdividef(e, s);
  }
}

template<bool U8OUT>
DI void attn_one_mfma(const BF8& qa0, const BF8& qa1,
                      const bf16* __restrict__ KT, const bf16* __restrict__ VT,
                      bf16* __restrict__ P,
                      const float* __restrict__ resid, void* outp, int lane)
{
  const int col = lane & 31, kg = lane >> 5;
  f32x16 acc;
  #pragma unroll
  for (int e = 0; e < 16; ++e) acc[e] = 0.f;
  BF8 kb0, kb1;
  kb0.v = *(const int4*)&KT[col * 40 + kg * 8];
  kb1.v = *(const int4*)&KT[col * 40 + 16 + kg * 8];
  acc = __builtin_amdgcn_mfma_f32_32x32x16_bf16(qa0.s, kb0.s, acc, 0, 0, 0);
  acc = __builtin_amdgcn_mfma_f32_32x32x16_bf16(qa1.s, kb1.s, acc, 0, 0, 0);
  float p[16];
  #pragma unroll
  for (int r = 0; r < 16; ++r) p[r] = acc[r];
  softmax_rows(p);
  __syncthreads();
  #pragma unroll
  for (int r = 0; r < 16; ++r) {
    int row = (r & 3) + 8 * (r >> 2) + 4 * kg;
    P[row * 40 + col] = __float2bfloat16(p[r]);
  }
  __syncthreads();
  BF8 pa0, pa1, vb0, vb1;
  pa0.v = *(const int4*)&P[col * 40 + kg * 8];
  pa1.v = *(const int4*)&P[col * 40 + 16 + kg * 8];
  vb0.v = *(const int4*)&VT[col * 40 + kg * 8];
  vb1.v = *(const int4*)&VT[col * 40 + 16 + kg * 8];
  #pragma unroll
  for (int e = 0; e < 16; ++e) acc[e] = 0.f;
  acc = __builtin_amdgcn_mfma_f32_32x32x16_bf16(pa0.s, vb0.s, acc, 0, 0, 0);
  acc = __builtin_amdgcn_mfma_f32_32x32x16_bf16(pa1.s, vb1.s, acc, 0, 0, 0);
  #pragma unroll
  for (int r = 0; r < 16; ++r) p[r] = acc[r];
  softmax_rows(p);
  if constexpr (!U8OUT) {
    bf16* op = (bf16*)outp;
    #pragma unroll
    for (int r = 0; r < 16; ++r) {
      int row = (r & 3) + 8 * (r >> 2) + 4 * kg;
      int off = row * 32 + col;
      op[off] = __float2bfloat16(p[r] + resid[off]);
    }
  } else {
    u8* op = (u8*)outp;
    #pragma unroll
    for (int r = 0; r < 16; ++r) {
      int row = (r & 3) + 8 * (r >> 2) + 4 * kg;
      op[row * 32 + col] = (u8)fminf(p[r] * 256.f + 0.5f, 255.f);
    }
  }
}

__global__ __launch_bounds__(64) void attn_mfma_kernel(
    const bf16* __restrict__ pc,
    const float* __restrict__ st, const float* __restrict__ phy,
    bf16* __restrict__ cA, u8* __restrict__ cB, int cb)
{
  __shared__ __align__(16) bf16 KTst[32 * 40], VTst[32 * 40];
  __shared__ __align__(16) bf16 KTph[32 * 40], VTph[32 * 40];
  __shared__ __align__(16) bf16 P[32 * 40];
  const int cl = blockIdx.x, b = blockIdx.y;
  const int c = cb + cl;
  const int lane = threadIdx.x;
  const size_t mstride = (size_t)128 * 32 * 1024;
  const bf16* p0 = pc + ((size_t)b * 32 + cl) * 1024;
  const size_t bc = ((size_t)b * 128 + c) * 1024;

  {
    const int w = lane >> 1, k0 = (lane & 1) * 16;
    const int off = w * 32 + k0;
    bf16* dsts[4] = { KTst, VTst, KTph, VTph };
    const int ms[4] = { 1, 2, 4, 5 };
    #pragma unroll
    for (int t = 0; t < 4; ++t) {
      BF8 r0, r1;
      r0.v = *(const int4*)&p0[(size_t)ms[t] * mstride + off];
      r1.v = *(const int4*)&p0[(size_t)ms[t] * mstride + off + 8];
      #pragma unroll
      for (int j = 0; j < 8; ++j) {
        dsts[t][(k0 + j) * 40 + w]     = r0.h[j];
        dsts[t][(k0 + 8 + j) * 40 + w] = r1.h[j];
      }
    }
  }
  const int col = lane & 31, kg = lane >> 5;
  BF8 qst0, qst1, qph0, qph1;
  qst0.v = *(const int4*)&p0[col * 32 + kg * 8];
  qst1.v = *(const int4*)&p0[col * 32 + 16 + kg * 8];
  qph0.v = *(const int4*)&p0[3 * mstride + col * 32 + kg * 8];
  qph1.v = *(const int4*)&p0[3 * mstride + col * 32 + 16 + kg * 8];
  __syncthreads();

  bf16* aA = cA + (size_t)b * 256 * 1024 + (size_t)c * 1024;
  u8*   aB = cB + (size_t)b * 256 * 1024 + (size_t)c * 1024;
  attn_one_mfma<false>(qst0, qst1, KTst, VTst, P, st + bc,  aA,          lane);
  attn_one_mfma<false>(qph0, qph1, KTph, VTph, P, phy + bc, aA + 131072, lane);
  attn_one_mfma<true >(qph0, qph1, KTst, VTst, P, nullptr,  aB,          lane);
  attn_one_mfma<true >(qst0, qst1, KTph, VTph, P, nullptr,  aB + 131072, lane);
}

// ---------------------------------------------------------------- concat transpose
__global__ __launch_bounds__(256) void transpose_kernel(
    const bf16* __restrict__ cA, const u8* __restrict__ cB,
    bf16* __restrict__ cAT, u8* __restrict__ cBT)
{
  __shared__ __align__(16) short Tb[64 * 72];
  __shared__ __align__(16) u8 T8[64 * 80];
  const int x = blockIdx.x, b = blockIdx.y;
  const int cht = x >> 4, post = x & 15;
  const int pos0 = post * 64;
  const int tid = threadIdx.x;
  const int rowi = tid >> 2, sub = tid & 3;

  if (cht < 4) {
    const int ch0 = cht * 64;
    const bf16* src = cA + ((size_t)b * 256 + ch0 + rowi) * 1024 + pos0 + sub * 16;
    *(int4*)&Tb[rowi * 72 + sub * 16]     = *(const int4*)src;
    *(int4*)&Tb[rowi * 72 + sub * 16 + 8] = *(const int4*)(src + 8);
    __syncthreads();
    short tmp[16];
    #pragma unroll
    for (int j = 0; j < 16; ++j) tmp[j] = Tb[(sub * 16 + j) * 72 + rowi];
    bf16* dst = cAT + ((size_t)b * 1024 + pos0 + rowi) * 256 + ch0 + sub * 16;
    *(int4*)dst       = ((int4*)tmp)[0];
    *(int4*)(dst + 8) = ((int4*)tmp)[1];
  } else {
    const int ch0 = (cht - 4) * 64;
    const u8* src = cB + ((size_t)b * 256 + ch0 + rowi) * 1024 + pos0 + sub * 16;
    *(int4*)&T8[rowi * 80 + sub * 16] = *(const int4*)src;
    __syncthreads();
    u8 tmp[16];
    #pragma unroll
    for (int j = 0; j < 16; ++j) tmp[j] = T8[(sub * 16 + j) * 80 + rowi];
    u8* dst = cBT + ((size_t)b * 1024 + pos0 + rowi) * 256 + ch0 + sub * 16;
    *(int4*)dst = *(int4*)tmp;
  }
}

// ---------------------------------------------------------------- fp8 conversion pass
__global__ __launch_bounds__(256) void to_fp8_kernel(
    const bf16* __restrict__ cAT, const u8* __restrict__ cBT,
    u8* __restrict__ cAT8)
{
  const int idx = blockIdx.x * 256 + threadIdx.x;
  const int g = idx & 31;
  const size_t bp = (size_t)(idx >> 5);
  const int c0 = g * 16;
  float v[16];
  if (c0 < 256) {
    BF8 lo, hi;
    lo.v = *(const int4*)&cAT[bp * 256 + c0];
    hi.v = *(const int4*)&cAT[bp * 256 + c0 + 8];
    #pragma unroll
    for (int j = 0; j < 8; ++j) {
      v[j]     = __bfloat162float(lo.h[j]) * 16.0f;
      v[8 + j] = __bfloat162float(hi.h[j]) * 16.0f;
    }
  } else {
    u64 raw0 = *(const u64*)&cBT[bp * 256 + (c0 - 256)];
    u64 raw1 = *(const u64*)&cBT[bp * 256 + (c0 - 256) + 8];
    #pragma unroll
    for (int j = 0; j < 8; ++j) {
      v[j]     = (float)((raw0 >> (8 * j)) & 255u) * 0.0625f;
      v[8 + j] = (float)((raw1 >> (8 * j)) & 255u) * 0.0625f;
    }
  }
  unsigned lo0 = (__builtin_amdgcn_cvt_pk_fp8_f32(v[0], v[1], 0, false) & 0xffff)
               | ((__builtin_amdgcn_cvt_pk_fp8_f32(v[2], v[3], 0, false) & 0xffff) << 16);
  unsigned hi0 = (__builtin_amdgcn_cvt_pk_fp8_f32(v[4], v[5], 0, false) & 0xffff)
               | ((__builtin_amdgcn_cvt_pk_fp8_f32(v[6], v[7], 0, false) & 0xffff) << 16);
  unsigned lo1 = (__builtin_amdgcn_cvt_pk_fp8_f32(v[8], v[9], 0, false) & 0xffff)
               | ((__builtin_amdgcn_cvt_pk_fp8_f32(v[10], v[11], 0, false) & 0xffff) << 16);
  unsigned hi1 = (__builtin_amdgcn_cvt_pk_fp8_f32(v[12], v[13], 0, false) & 0xffff)
               | ((__builtin_amdgcn_cvt_pk_fp8_f32(v[14], v[15], 0, false) & 0xffff) << 16);
  u64 run0 = (u64)lo0 | ((u64)hi0 << 32);
  u64 run1 = (u64)lo1 | ((u64)hi1 << 32);
  const int sp = (c0 >> 4) & 1;
  u8* d = cAT8 + bp * 512 + (c0 & ~31);
  *(u64*)(d + 8 * sp)      = run0;
  *(u64*)(d + 16 + 8 * sp) = run1;
}

// ---------------------------------------------------------------- staging (bf16)
template<int PCX, int NIT, int H0>
DI void stage_tile(const bf16* cAT, const u8* cBT, short* Xs,
                   int b, int r0, int ic0, int tid)
{
  for (int e = tid; e < NIT; e += 256) {
    int i = e / (PCX * 4);
    int rem = e - i * (PCX * 4);
    int cx = rem >> 2, part = rem & 3;
    int ir = r0 - H0 + i, c = cx - H0;
    int4 val = make_int4(0, 0, 0, 0);
    if ((unsigned)ir < 32u && (unsigned)c < 32u) {
      size_t pbase = ((size_t)b * 1024 + ir * 32 + c) * 256;
      if (ic0 < 256) {
        val = *(const int4*)&cAT[pbase + ic0 + part * 8];
      } else {
        u64 u = *(const u64*)&cBT[pbase + (ic0 - 256) + part * 8];
        BF8 t;
        #pragma unroll
        for (int j = 0; j < 8; ++j)
          t.h[j] = __float2bfloat16((float)((u >> (8 * j)) & 255u) * 0.00390625f);
        val = t.v;
      }
    }
    *(int4*)&Xs[(i * PCX + cx) * 40 + part * 8] = val;
  }
}

// ---------------------------------------------------------------- bf16 MFMA conv (conv1)
template<int KS>
__global__ __launch_bounds__(256, 2) void conv_mfma(
    const bf16* __restrict__ cAT, const u8* __restrict__ cBT,
    const bf16* __restrict__ wt, const float* __restrict__ bias,
    bf16* __restrict__ xout, float* __restrict__ partials)
{
  constexpr int H0 = KS / 2;
  constexpr int PCX = 32 + 2 * H0;
  constexpr int ROWS = 16 + 2 * H0;
  constexpr int NIT = ROWS * PCX * 4;
  __shared__ __align__(16) short Xs[ROWS * PCX * 40];
  __shared__ float rs[256], rq[256];
  const int h = blockIdx.x;
  const int logical = (h & 7) * 64 + (h >> 3);
  const int b = logical >> 2, tix = logical & 3;
  const int ot = tix >> 1, rt = tix & 1;
  const int oc0 = ot * 64, r0 = rt * 16;
  const int tid = threadIdx.x;
  const int wv = tid >> 6, lane = tid & 63;
  const int col = lane & 31, kg = lane >> 5;

  f32x16 acc[2][4];
  #pragma unroll
  for (int i = 0; i < 2; ++i)
    #pragma unroll
    for (int j = 0; j < 4; ++j)
      #pragma unroll
      for (int e = 0; e < 16; ++e) acc[i][j][e] = 0.f;

  for (int cc = 0; cc < 16; ++cc) {
    const int ic0 = cc * 32;
    stage_tile<PCX, NIT, H0>(cAT, cBT, Xs, b, r0, ic0, tid);
    __syncthreads();

    #pragma unroll 1
    for (int ky = 0; ky < KS; ++ky) {
      #pragma unroll
      for (int kx = 0; kx < KS; ++kx) {
        const int tap = ky * KS + kx;
        BF8 a[2][2];
        #pragma unroll
        for (int ob = 0; ob < 2; ++ob)
          #pragma unroll
          for (int kt = 0; kt < 2; ++kt) {
            int icg = cc * 4 + kt * 2 + kg;
            a[ob][kt].v = *(const int4*)&wt[(((size_t)tap * 64 + icg) * 128 + oc0 + ob * 32 + col) * 8];
          }
        #pragma unroll
        for (int rr = 0; rr < 4; ++rr) {
          int entry = ((wv * 4 + rr + ky) * PCX + col + kx) * 40;
          #pragma unroll
          for (int kt = 0; kt < 2; ++kt) {
            short8 bf = *(const short8*)&Xs[entry + (kt * 2 + kg) * 8];
            acc[0][rr] = __builtin_amdgcn_mfma_f32_32x32x16_bf16(a[0][kt].s, bf, acc[0][rr], 0, 0, 0);
            acc[1][rr] = __builtin_amdgcn_mfma_f32_32x32x16_bf16(a[1][kt].s, bf, acc[1][rr], 0, 0, 0);
          }
        }
      }
    }
    __syncthreads();
  }

  float lsum = 0.f, lsq = 0.f;
  #pragma unroll
  for (int ob = 0; ob < 2; ++ob)
    #pragma unroll
    for (int rr = 0; rr < 4; ++rr) {
      const int row = r0 + wv * 4 + rr;
      #pragma unroll
      for (int r = 0; r < 16; ++r) {
        const int oc = oc0 + ob * 32 + (r & 3) + 8 * (r >> 2) + 4 * kg;
        float v = acc[ob][rr][r];
        if (bias) v += bias[oc];
        xout[((size_t)b * 128 + oc) * 1024 + row * 32 + col] = __float2bfloat16(v);
        lsum += v; lsq += v * v;
      }
    }
  rs[tid] = lsum; rq[tid] = lsq;
  __syncthreads();
  for (int s = 128; s > 0; s >>= 1) {
    if (tid < s) { rs[tid] += rs[tid + s]; rq[tid] += rq[tid + s]; }
    __syncthreads();
  }
  if (tid == 0) {
    partials[((size_t)b * 4 + tix) * 2]     = rs[0];
    partials[((size_t)b * 4 + tix) * 2 + 1] = rq[0];
  }
}

// ---------------------------------------------------------------- MX fp8 conv (KS=3,5,7)
// R13-proven shape: ob=2 x rr=4, 16-row tiles, grid 512 XCD-swizzled,
// 2 blocks/CU, LDS entry = 64 B data + 16 pad (80 B stride). A and B operand
// pipes balanced (~512 cy each) under MFMA (~1100 cy) -> 64% MfmaUtil.
template<int KS>
__global__ __launch_bounds__(256, 2) void conv_mx(
    const u8* __restrict__ cAT8, const u8* __restrict__ wf,
    bf16* __restrict__ xout, float* __restrict__ partials)
{
  constexpr int H0 = KS / 2;
  constexpr int PCX = 32 + 2 * H0;
  constexpr int ROWS = 16 + 2 * H0;
  constexpr int NIT = ROWS * PCX * 4;              // 16-B units
  __shared__ __align__(16) u8 Xs[ROWS * PCX * 80];
  __shared__ float rs[256], rq[256];
  const int h = blockIdx.x;
  const int logical = (h & 7) * 64 + (h >> 3);
  const int b = logical >> 2, tix = logical & 3;
  const int ot = tix >> 1, rt = tix & 1;
  const int oc0 = ot * 64, r0 = rt * 16;
  const int tid = threadIdx.x;
  const int wv = tid >> 6, lane = tid & 63;
  const int col = lane & 31, g = lane >> 5;

  f32x16 acc[2][4];
  #pragma unroll
  for (int i = 0; i < 2; ++i)
    #pragma unroll
    for (int j = 0; j < 4; ++j)
      #pragma unroll
      for (int e = 0; e < 16; ++e) acc[i][j][e] = 0.f;

  for (int cc2 = 0; cc2 < 8; ++cc2) {
    for (int e = tid; e < NIT; e += 256) {
      int entry = e >> 2, hf = e & 3;
      int i = entry / PCX, cx = entry - i * PCX;
      int ir = r0 - H0 + i, c = cx - H0;
      int4 val = make_int4(0, 0, 0, 0);
      if ((unsigned)ir < 32u && (unsigned)c < 32u)
        val = *(const int4*)&cAT8[((size_t)b * 1024 + ir * 32 + c) * 512 + cc2 * 64 + hf * 16];
      *(int4*)&Xs[entry * 80 + hf * 16] = val;
    }
    __syncthreads();

    #pragma unroll 1
    for (int ky = 0; ky < KS; ++ky) {
      #pragma unroll
      for (int kx = 0; kx < KS; ++kx) {
        const int tap = ky * KS + kx;
        const size_t wbase = (((size_t)tap * 8 + cc2) * 2 + g) * 128;
        U32B a0, a1;
        a0.v[0] = *(const int4*)&wf[(wbase + oc0 + col) * 32];
        a0.v[1] = *(const int4*)&wf[(wbase + oc0 + col) * 32 + 16];
        a1.v[0] = *(const int4*)&wf[(wbase + oc0 + 32 + col) * 32];
        a1.v[1] = *(const int4*)&wf[(wbase + oc0 + 32 + col) * 32 + 16];
        #pragma unroll
        for (int rr = 0; rr < 4; ++rr) {
          const int ebase = ((wv * 4 + rr + ky) * PCX + col + kx) * 80 + g * 32;
          U32B bf;
          bf.v[0] = *(const int4*)&Xs[ebase];
          bf.v[1] = *(const int4*)&Xs[ebase + 16];
          acc[0][rr] = __builtin_amdgcn_mfma_scale_f32_32x32x64_f8f6f4(
              a0.w, bf.w, acc[0][rr], 0, 0, 0, 0x7f7f7f7f, 0, 0x7f7f7f7f);
          acc[1][rr] = __builtin_amdgcn_mfma_scale_f32_32x32x64_f8f6f4(
              a1.w, bf.w, acc[1][rr], 0, 0, 0, 0x7f7f7f7f, 0, 0x7f7f7f7f);
        }
      }
    }
    __syncthreads();
  }

  float lsum = 0.f, lsq = 0.f;
  #pragma unroll
  for (int ob = 0; ob < 2; ++ob)
    #pragma unroll
    for (int rr = 0; rr < 4; ++rr) {
      const int row = r0 + wv * 4 + rr;
      #pragma unroll
      for (int r = 0; r < 16; ++r) {
        const int oc = oc0 + ob * 32 + (r & 3) + 8 * (r >> 2) + 4 * g;
        float v = acc[ob][rr][r] * (1.0f / 4096.0f);
        xout[((size_t)b * 128 + oc) * 1024 + row * 32 + col] = __float2bfloat16(v);
        lsum += v; lsq += v * v;
      }
    }
  rs[tid] = lsum; rq[tid] = lsq;
  __syncthreads();
  for (int s = 128; s > 0; s >>= 1) {
    if (tid < s) { rs[tid] += rs[tid + s]; rq[tid] += rq[tid + s]; }
    __syncthreads();
  }
  if (tid == 0) {
    partials[((size_t)b * 4 + tix) * 2]     = rs[0];
    partials[((size_t)b * 4 + tix) * 2 + 1] = rq[0];
  }
}

// ---------------------------------------------------------------- LN + combine (4 partials each)
__global__ __launch_bounds__(256) void final_kernel(
    const bf16* __restrict__ x3, const bf16* __restrict__ x5,
    const bf16* __restrict__ x7, const bf16* __restrict__ x1c,
    const float* __restrict__ p3, const float* __restrict__ p5,
    const float* __restrict__ p7, const float* __restrict__ p1,
    const float* __restrict__ g3, const float* __restrict__ be3,
    const float* __restrict__ g5, const float* __restrict__ be5,
    const float* __restrict__ g7, const float* __restrict__ be7,
    const float* __restrict__ g1, const float* __restrict__ be1,
    float* __restrict__ out)
{
  const int blk = blockIdx.x, b = blockIdx.y, tid = threadIdx.x;
  float s3 = 0, q3 = 0, s5 = 0, q5 = 0, s7 = 0, q7 = 0, s1 = 0, q1 = 0;
  #pragma unroll
  for (int i = 0; i < 4; ++i) {
    int o = (b * 4 + i) * 2;
    s3 += p3[o]; q3 += p3[o + 1];
    s5 += p5[o]; q5 += p5[o + 1];
    s7 += p7[o]; q7 += p7[o + 1];
    s1 += p1[o]; q1 += p1[o + 1];
  }
  const float inv = 1.0f / 131072.0f;
  float mu3 = s3 * inv, r3 = rsqrtf(fmaxf(q3 * inv - mu3 * mu3, 0.f) + 1e-5f);
  float mu5 = s5 * inv, r5 = rsqrtf(fmaxf(q5 * inv - mu5 * mu5, 0.f) + 1e-5f);
  float mu7 = s7 * inv, r7 = rsqrtf(fmaxf(q7 * inv - mu7 * mu7, 0.f) + 1e-5f);
  float mu1 = s1 * inv, r1 = rsqrtf(fmaxf(q1 * inv - mu1 * mu1, 0.f) + 1e-5f);
  const size_t bb = (size_t)b * 131072;
  for (int it = 0; it < 8; ++it) {
    int e0 = (it * 2048 + blk * 256 + tid) * 8;
    BF8 a3, a5, a7, a1;
    a3.v = *(const int4*)&x3[bb + e0];
    a5.v = *(const int4*)&x5[bb + e0];
    a7.v = *(const int4*)&x7[bb + e0];
    a1.v = *(const int4*)&x1c[bb + e0];
    float G3[8], B3[8], G5[8], B5[8], G7[8], B7[8], G1[8], B1[8];
    *(float4*)&G3[0] = *(const float4*)&g3[e0];  *(float4*)&G3[4] = *(const float4*)&g3[e0 + 4];
    *(float4*)&B3[0] = *(const float4*)&be3[e0]; *(float4*)&B3[4] = *(const float4*)&be3[e0 + 4];
    *(float4*)&G5[0] = *(const float4*)&g5[e0];  *(float4*)&G5[4] = *(const float4*)&g5[e0 + 4];
    *(float4*)&B5[0] = *(const float4*)&be5[e0]; *(float4*)&B5[4] = *(const float4*)&be5[e0 + 4];
    *(float4*)&G7[0] = *(const float4*)&g7[e0];  *(float4*)&G7[4] = *(const float4*)&g7[e0 + 4];
    *(float4*)&B7[0] = *(const float4*)&be7[e0]; *(float4*)&B7[4] = *(const float4*)&be7[e0 + 4];
    *(float4*)&G1[0] = *(const float4*)&g1[e0];  *(float4*)&G1[4] = *(const float4*)&g1[e0 + 4];
    *(float4*)&B1[0] = *(const float4*)&be1[e0]; *(float4*)&B1[4] = *(const float4*)&be1[e0 + 4];
    float res[8];
    #pragma unroll
    for (int j = 0; j < 8; ++j) {
      float v3 = (__bfloat162float(a3.h[j]) - mu3) * r3 * G3[j] + B3[j];
      float v5 = (__bfloat162float(a5.h[j]) - mu5) * r5 * G5[j] + B5[j];
      float v7 = (__bfloat162float(a7.h[j]) - mu7) * r7 * G7[j] + B7[j];
      float m = (v3 + v5 + v7) * (1.0f / 3.0f);
      float sg = 1.0f / (1.0f + __expf(-m));
      float v1 = (__bfloat162float(a1.h[j]) - mu1) * r1 * G1[j] + B1[j];
      res[j] = sg + v1;
    }
    *(float4*)&out[bb + e0]     = make_float4(res[0], res[1], res[2], res[3]);
    *(float4*)&out[bb + e0 + 4] = make_float4(res[4], res[5], res[6], res[7]);
  }
}

// ---------------------------------------------------------------- launch
extern "C" void kernel_launch(void* const* d_in, const int* in_sizes, int n_in,
                              void* d_out, int out_size, void* d_ws, size_t ws_size,
                              hipStream_t stream)
{
  (void)in_sizes; (void)n_in; (void)out_size; (void)ws_size;
  const float* st     = (const float*)d_in[0];
  const float* phy    = (const float*)d_in[1];
  const float* wq_st  = (const float*)d_in[2];
  const float* bq_st  = (const float*)d_in[3];
  const float* wk_st  = (const float*)d_in[4];
  const float* bk_st  = (const float*)d_in[5];
  const float* wv_st  = (const float*)d_in[6];
  const float* bv_st  = (const float*)d_in[7];
  const float* wq_phy = (const float*)d_in[8];
  const float* bq_phy = (const float*)d_in[9];
  const float* wk_phy = (const float*)d_in[10];
  const float* bk_phy = (const float*)d_in[11];
  const float* wv_phy = (const float*)d_in[12];
  const float* bv_phy = (const float*)d_in[13];
  const float* w3  = (const float*)d_in[14];
  const float* g3  = (const float*)d_in[15];
  const float* be3 = (const float*)d_in[16];
  const float* w5  = (const float*)d_in[17];
  const float* g5  = (const float*)d_in[18];
  const float* be5 = (const float*)d_in[19];
  const float* w7  = (const float*)d_in[20];
  const float* g7  = (const float*)d_in[21];
  const float* be7 = (const float*)d_in[22];
  const float* w1  = (const float*)d_in[23];
  const float* g1  = (const float*)d_in[24];
  const float* be1 = (const float*)d_in[25];
  const float* b1  = (const float*)d_in[26];

  char* ws = (char*)d_ws;
  // phase A
  bf16* Xt        = (bf16*)ws;
  bf16* projchunk = (bf16*)(ws + 67108864ULL);
  bf16* cA        = (bf16*)(ws + 117440512ULL);
  u8*   cB        = (u8*)(ws + 184549376ULL);
  bf16* wproj     = (bf16*)(ws + 218103808ULL);
  // phase B/C
  bf16* cAT       = (bf16*)ws;
  u8*   cBT       = (u8*)(ws + 67108864ULL);
  u8*   cAT8      = (u8*)(ws + 117440512ULL);
  bf16* x1b       = (bf16*)(ws + 184549376ULL);
  bf16* x3b       = (bf16*)ws;
  bf16* x5b       = (bf16*)(ws + 33554432ULL);
  bf16* x7b       = (bf16*)(ws + 67108864ULL);
  float* parts    = (float*)(ws + 234881024ULL);
  u8*   wf3       = (u8*)(ws + 234913792ULL);
  u8*   wf5       = (u8*)(ws + 236093440ULL);
  u8*   wf7       = (u8*)(ws + 239370240ULL);
  bf16* wb1       = (bf16*)(ws + 245792768ULL);

  prep_w_kernel<<<dim3(2048), 256, 0, stream>>>(w3, w5, w7, w1,
      wq_st, wk_st, wv_st, wq_phy, wk_phy, wv_phy,
      wf3, wf5, wf7, wb1, wproj);
  xpose_in_kernel<<<dim3(64, 128), 256, 0, stream>>>(st, phy, Xt);

  for (int g = 0; g < 4; ++g) {
    proj_mfma<<<dim3(8, 128), 256, 0, stream>>>(Xt, wproj,
        bq_st, bk_st, bv_st, bq_phy, bk_phy, bv_phy, projchunk, g * 32);
    attn_mfma_kernel<<<dim3(32, 128), 64, 0, stream>>>(projchunk, st, phy,
        cA, cB, g * 32);
  }
  transpose_kernel<<<dim3(128, 128), 256, 0, stream>>>(cA, cB, cAT, cBT);
  to_fp8_kernel<<<dim3(16384), 256, 0, stream>>>(cAT, cBT, cAT8);

  conv_mfma<1><<<dim3(512), 256, 0, stream>>>(cAT, cBT, wb1, b1, x1b, parts + 6144);
  conv_mx<3><<<dim3(512), 256, 0, stream>>>(cAT8, wf3, x3b, parts);
  conv_mx<5><<<dim3(512), 256, 0, stream>>>(cAT8, wf5, x5b, parts + 2048);
  conv_mx<7><<<dim3(512), 256, 0, stream>>>(cAT8, wf7, x7b, parts + 4096);

  final_kernel<<<dim3(8, 128), 256, 0, stream>>>(x3b, x5b, x7b, x1b,
      parts, parts + 2048, parts + 4096, parts + 6144,
      g3, be3, g5, be5, g7, be7, g1, be1, (float*)d_out);
}